// Round 1
// baseline (32312.561 us; speedup 1.0000x reference)
//
#include <hip/hip_runtime.h>
#include <math.h>

#define NPTS 8192
#define KNN 20

// ---------------------------------------------------------------------------
// sq[i] = sum_d x[i][d]^2
// ---------------------------------------------------------------------------
__global__ void sqnorm_kernel(const float* __restrict__ x, int ldx, int D,
                              float* __restrict__ sq) {
  int i = blockIdx.x * blockDim.x + threadIdx.x;
  if (i >= NPTS) return;
  const float* xr = x + (size_t)i * ldx;
  float s = 0.f;
  for (int d = 0; d < D; ++d) { float v = xr[d]; s += v * v; }
  sq[i] = s;
}

// ---------------------------------------------------------------------------
// kNN: for each row i, indices of the 20 smallest d(i,j), j != i.
// d_rank = sq[j] - 2*dot(x_i, x_j)  (row-constant shift of the reference's
// sq_i + sq_j - 2 dot -> identical ranking). Tie-break: smaller j (matches
// lax.top_k). 2 rows per block, 512 threads, 16 candidates per lane held in
// registers; 20 rounds of block argmin.
// ---------------------------------------------------------------------------
template <int D>
__global__ __launch_bounds__(512) void knn_kernel(const float* __restrict__ x,
                                                  int ldx,
                                                  const float* __restrict__ sq,
                                                  int* __restrict__ idx_out) {
  constexpr int ROWS = 2;
  constexpr int T = NPTS / 512;  // 16 candidates per lane
  const int tid = threadIdx.x;
  const int lane = tid & 63;
  const int wv = tid >> 6;  // 0..7
  const int i0 = blockIdx.x * ROWS;

  __shared__ float s_xi[ROWS][D];
  __shared__ float s_v[8];
  __shared__ int s_j[8];
  __shared__ int s_win;

  for (int t = tid; t < ROWS * D; t += 512)
    s_xi[t / D][t % D] = x[(size_t)(i0 + t / D) * ldx + (t % D)];
  __syncthreads();

  float dist[ROWS][T];
#pragma unroll
  for (int t = 0; t < T; ++t) {
    const int j = tid + t * 512;
    float a0 = 0.f, a1 = 0.f;
    if constexpr (D % 4 == 0) {
      const float4* __restrict__ xj4 = (const float4*)(x + (size_t)j * ldx);
#pragma unroll
      for (int dc = 0; dc < D / 4; ++dc) {
        float4 v = xj4[dc];
        const float4 p0 = *(const float4*)&s_xi[0][dc * 4];
        const float4 p1 = *(const float4*)&s_xi[1][dc * 4];
        a0 += p0.x * v.x + p0.y * v.y + p0.z * v.z + p0.w * v.w;
        a1 += p1.x * v.x + p1.y * v.y + p1.z * v.z + p1.w * v.w;
      }
    } else {
      const float* __restrict__ xj = x + (size_t)j * ldx;
#pragma unroll
      for (int d = 0; d < D; ++d) {
        float v = xj[d];
        a0 += s_xi[0][d] * v;
        a1 += s_xi[1][d] * v;
      }
    }
    float sqj = sq[j];
    dist[0][t] = (j == i0) ? INFINITY : fmaf(-2.f, a0, sqj);
    dist[1][t] = (j == i0 + 1) ? INFINITY : fmaf(-2.f, a1, sqj);
  }

#pragma unroll
  for (int r = 0; r < ROWS; ++r) {
    for (int s = 0; s < KNN; ++s) {
      float bv = INFINITY;
      int bj = 0x7fffffff;
#pragma unroll
      for (int t = 0; t < T; ++t) {
        float v = dist[r][t];
        if (v < bv) { bv = v; bj = tid + t * 512; }  // ascending j: keeps min j on ties
      }
#pragma unroll
      for (int o = 32; o >= 1; o >>= 1) {
        float ov = __shfl_down(bv, o, 64);
        int oj = __shfl_down(bj, o, 64);
        if (ov < bv || (ov == bv && oj < bj)) { bv = ov; bj = oj; }
      }
      if (lane == 0) { s_v[wv] = bv; s_j[wv] = bj; }
      __syncthreads();
      if (tid == 0) {
        float fv = s_v[0];
        int fj = s_j[0];
#pragma unroll
        for (int w = 1; w < 8; ++w) {
          float ov = s_v[w];
          int oj = s_j[w];
          if (ov < fv || (ov == fv && oj < fj)) { fv = ov; fj = oj; }
        }
        idx_out[(size_t)(i0 + r) * KNN + s] = fj;
        s_win = fj;
      }
      __syncthreads();
      int win = s_win;
      if (((win ^ tid) & 511) == 0) {
#pragma unroll
        for (int t = 0; t < T; ++t)
          if (win == tid + t * 512) dist[r][t] = INFINITY;
      }
      // no trailing barrier needed: next round's first __syncthreads orders
      // the s_v/s_win reuse (reads of this round happen-before it).
    }
  }
}

// ---------------------------------------------------------------------------
// edge conv: out[i][c] = max_k relu(b + [x_i, x_j-x_i] . W1[:,c])
// ---------------------------------------------------------------------------
__global__ __launch_bounds__(64) void edgeconv_kernel(
    const float* __restrict__ x, const int* __restrict__ idx,
    const float* __restrict__ W1, const float* __restrict__ b1,
    float* __restrict__ out) {
  const int i = blockIdx.x;
  const int c = threadIdx.x;  // 0..63
  float w0 = W1[c], w1 = W1[64 + c], w2 = W1[128 + c];
  float w3 = W1[192 + c], w4 = W1[256 + c], w5 = W1[320 + c];
  float xi0 = x[3 * i], xi1 = x[3 * i + 1], xi2 = x[3 * i + 2];
  float base = b1[c] + xi0 * w0 + xi1 * w1 + xi2 * w2;
  float m = -INFINITY;
#pragma unroll
  for (int k = 0; k < KNN; ++k) {
    int j = idx[i * KNN + k];
    float d0 = x[3 * j] - xi0, d1 = x[3 * j + 1] - xi1, d2 = x[3 * j + 2] - xi2;
    float h = base + d0 * w3 + d1 * w4 + d2 * w5;
    m = fmaxf(m, fmaxf(h, 0.f));
  }
  out[(size_t)i * 64 + c] = m;
}

// ---------------------------------------------------------------------------
// dilate: dil[c] = max_k xin[idx[k]][c]; out[i][c] = relu(dil.W[:,c]+b) - xin[i][c]
// ---------------------------------------------------------------------------
__global__ __launch_bounds__(64) void dilate_kernel(
    const float* __restrict__ xin, int ldin, const int* __restrict__ idx,
    const float* __restrict__ W, const float* __restrict__ bias,
    float* __restrict__ out, int ldout) {
  const int i = blockIdx.x;
  const int c = threadIdx.x;
  __shared__ float dil[64];
  float m = -INFINITY;
#pragma unroll
  for (int k = 0; k < KNN; ++k) {
    int j = idx[i * KNN + k];
    m = fmaxf(m, xin[(size_t)j * ldin + c]);
  }
  dil[c] = m;
  __syncthreads();
  float acc = bias[c];
#pragma unroll
  for (int d = 0; d < 64; ++d) acc = fmaf(dil[d], W[d * 64 + c], acc);
  out[(size_t)i * ldout + c] = fmaxf(acc, 0.f) - xin[(size_t)i * ldin + c];
}

// ---------------------------------------------------------------------------
// C[M x N] = (relu?) (A[M x K] @ W[K x N] + bias). BM=BN=64, BK=16, 256 thr,
// 4x4 per thread. All dims here are multiples of the tiles.
// ---------------------------------------------------------------------------
__global__ __launch_bounds__(256) void gemm_relu_kernel(
    const float* __restrict__ A, int K, int ldA, const float* __restrict__ W,
    int N, const float* __restrict__ bias, float* __restrict__ C, int ldC,
    int relu) {
  __shared__ float As[16][68];  // [k][m], pad 68 -> 2-way-max bank pattern
  __shared__ float Bs[16][64];  // [k][n]
  const int bn = blockIdx.x * 64;
  const int bm = blockIdx.y * 64;
  const int tid = threadIdx.x;
  const int tx = tid & 15, ty = tid >> 4;
  float acc[4][4] = {};
  for (int k0 = 0; k0 < K; k0 += 16) {
#pragma unroll
    for (int l = tid; l < 1024; l += 256) {
      int m = l >> 4, k = l & 15;
      As[k][m] = A[(size_t)(bm + m) * ldA + k0 + k];
    }
#pragma unroll
    for (int l = tid; l < 1024; l += 256) {
      int n = l & 63, k = l >> 6;
      Bs[k][n] = W[(size_t)(k0 + k) * N + bn + n];
    }
    __syncthreads();
#pragma unroll
    for (int k = 0; k < 16; ++k) {
      float4 av = *(const float4*)&As[k][ty * 4];
      float4 bv = *(const float4*)&Bs[k][tx * 4];
      float a[4] = {av.x, av.y, av.z, av.w};
      float b[4] = {bv.x, bv.y, bv.z, bv.w};
#pragma unroll
      for (int u = 0; u < 4; ++u)
#pragma unroll
        for (int v = 0; v < 4; ++v) acc[u][v] = fmaf(a[u], b[v], acc[u][v]);
    }
    __syncthreads();
  }
#pragma unroll
  for (int u = 0; u < 4; ++u) {
    int m = bm + ty * 4 + u;
#pragma unroll
    for (int v = 0; v < 4; ++v) {
      int n = bn + tx * 4 + v;
      float val = acc[u][v] + bias[n];
      if (relu) val = fmaxf(val, 0.f);
      C[(size_t)m * ldC + n] = val;
    }
  }
}

// ---------------------------------------------------------------------------
// logits = h3 @ Wm3 + bm3 ; out = log_softmax(logits). 16 rows/block,
// 16 threads per row (shfl_xor width 16 for the row reduction).
// ---------------------------------------------------------------------------
__global__ __launch_bounds__(256) void final_kernel(
    const float* __restrict__ h3, const float* __restrict__ Wm3,
    const float* __restrict__ bm3, float* __restrict__ out) {
  __shared__ float hs[16][132];  // pad: r-groups hit distinct banks
  const int tid = threadIdx.x;
  const int r = tid >> 4, c = tid & 15;
  const int row0 = blockIdx.x * 16;
#pragma unroll
  for (int l = tid; l < 2048; l += 256)
    hs[l >> 7][l & 127] = h3[(size_t)row0 * 128 + l];
  __syncthreads();
  float acc = bm3[c];
#pragma unroll
  for (int d = 0; d < 128; ++d) acc = fmaf(hs[r][d], Wm3[d * 16 + c], acc);
  float mx = acc;
#pragma unroll
  for (int o = 8; o >= 1; o >>= 1) mx = fmaxf(mx, __shfl_xor(mx, o, 16));
  float e = expf(acc - mx);
  float s = e;
#pragma unroll
  for (int o = 8; o >= 1; o >>= 1) s += __shfl_xor(s, o, 16);
  out[(size_t)(row0 + r) * 16 + c] = (acc - mx) - logf(s);
}

// ---------------------------------------------------------------------------
extern "C" void kernel_launch(void* const* d_in, const int* in_sizes, int n_in,
                              void* d_out, int out_size, void* d_ws,
                              size_t ws_size, hipStream_t stream) {
  const float* x = (const float*)d_in[0];
  const float* W1 = (const float*)d_in[1];
  const float* b1 = (const float*)d_in[2];
  const float* Wd1 = (const float*)d_in[3];
  const float* bd1 = (const float*)d_in[4];
  const float* Wd2 = (const float*)d_in[5];
  const float* bd2 = (const float*)d_in[6];
  const float* Wd3 = (const float*)d_in[7];
  const float* bd3 = (const float*)d_in[8];
  const float* Wl = (const float*)d_in[9];
  const float* bl = (const float*)d_in[10];
  const float* Wm1 = (const float*)d_in[11];
  const float* bm1 = (const float*)d_in[12];
  const float* Wm2 = (const float*)d_in[13];
  const float* bm2 = (const float*)d_in[14];
  const float* Wm3 = (const float*)d_in[15];
  const float* bm3 = (const float*)d_in[16];
  float* out = (float*)d_out;

  // workspace layout (bytes); total ~53.3 MB
  char* ws = (char*)d_ws;
  float* sq = (float*)(ws + 0);              // 32 KB
  int* idxA = (int*)(ws + 32768);            // 640 KB
  int* idxB = (int*)(ws + 688128);           // 640 KB
  float* xfeat = (float*)(ws + 1343488);     // 2 MB   [8192 x 64]
  float* xcat = (float*)(ws + 3440640);      // 6 MB   [8192 x 192] = [x1|x2|x3]
  float* h1 = (float*)(ws + 9732096);        // 32 MB  [8192 x 1024]
  float* h2 = (float*)(ws + 43286528);       // 8 MB   [8192 x 256]
  float* h3 = (float*)(ws + 51675136);       // 4 MB   [8192 x 128]
  float* x1 = xcat;
  float* x2 = xcat + 64;
  float* x3 = xcat + 128;

  // stage 1: edge conv on xyz
  sqnorm_kernel<<<32, 256, 0, stream>>>(x, 3, 3, sq);
  knn_kernel<3><<<NPTS / 2, 512, 0, stream>>>(x, 3, sq, idxA);
  edgeconv_kernel<<<NPTS, 64, 0, stream>>>(x, idxA, W1, b1, xfeat);

  // stage 2: dilate blocks (kNN in 64-D feature space each time)
  sqnorm_kernel<<<32, 256, 0, stream>>>(xfeat, 64, 64, sq);
  knn_kernel<64><<<NPTS / 2, 512, 0, stream>>>(xfeat, 64, sq, idxB);
  dilate_kernel<<<NPTS, 64, 0, stream>>>(xfeat, 64, idxB, Wd1, bd1, x1, 192);

  sqnorm_kernel<<<32, 256, 0, stream>>>(x1, 192, 64, sq);
  knn_kernel<64><<<NPTS / 2, 512, 0, stream>>>(x1, 192, sq, idxA);
  dilate_kernel<<<NPTS, 64, 0, stream>>>(x1, 192, idxA, Wd2, bd2, x2, 192);

  sqnorm_kernel<<<32, 256, 0, stream>>>(x2, 192, 64, sq);
  knn_kernel<64><<<NPTS / 2, 512, 0, stream>>>(x2, 192, sq, idxB);
  dilate_kernel<<<NPTS, 64, 0, stream>>>(x2, 192, idxB, Wd3, bd3, x3, 192);

  // stage 3: MLP head
  gemm_relu_kernel<<<dim3(1024 / 64, NPTS / 64), 256, 0, stream>>>(
      xcat, 192, 192, Wl, 1024, bl, h1, 1024, 1);
  gemm_relu_kernel<<<dim3(256 / 64, NPTS / 64), 256, 0, stream>>>(
      h1, 1024, 1024, Wm1, 256, bm1, h2, 256, 1);
  gemm_relu_kernel<<<dim3(128 / 64, NPTS / 64), 256, 0, stream>>>(
      h2, 256, 256, Wm2, 128, bm2, h3, 128, 1);
  final_kernel<<<NPTS / 16, 256, 0, stream>>>(h3, Wm3, bm3, out);
}

// Round 2
// 3464.211 us; speedup vs baseline: 9.3275x; 9.3275x over previous
//
#include <hip/hip_runtime.h>
#include <math.h>

#define NPTS 8192
#define KNN 20

// ---------------------------------------------------------------------------
// sq[i] = sum_d x[i][d]^2
// ---------------------------------------------------------------------------
__global__ void sqnorm_kernel(const float* __restrict__ x, int ldx, int D,
                              float* __restrict__ sq) {
  int i = blockIdx.x * blockDim.x + threadIdx.x;
  if (i >= NPTS) return;
  const float* xr = x + (size_t)i * ldx;
  float s = 0.f;
  for (int d = 0; d < D; ++d) { float v = xr[d]; s += v * v; }
  sq[i] = s;
}

// ---------------------------------------------------------------------------
// Branchless sorted-insert (ascending). Caller guards with val < d[19].
// Strict < keeps earlier-scanned (smaller j) entries ahead on ties.
// ---------------------------------------------------------------------------
__device__ __forceinline__ void insert20(float (&d)[KNN], int (&ix)[KNN],
                                         float val, int j) {
  float cv = val; int ci = j;
#pragma unroll
  for (int r = 0; r < KNN; ++r) {
    bool sw = cv < d[r];
    float od = d[r]; int oi = ix[r];
    d[r] = sw ? cv : od; ix[r] = sw ? ci : oi;
    cv = sw ? od : cv;  ci = sw ? oi : ci;
  }
}

// tie-aware version for the merge (dist, then index)
__device__ __forceinline__ void insert20t(float (&d)[KNN], int (&ix)[KNN],
                                          float val, int j) {
  float cv = val; int ci = j;
#pragma unroll
  for (int r = 0; r < KNN; ++r) {
    bool sw = (cv < d[r]) || (cv == d[r] && ci < ix[r]);
    float od = d[r]; int oi = ix[r];
    d[r] = sw ? cv : od; ix[r] = sw ? ci : oi;
    cv = sw ? od : cv;  ci = sw ? oi : ci;
  }
}

// ---------------------------------------------------------------------------
// 64-D kNN pass as a fused fp32 GEMM + top-20 selection.
// Grid: (64 query-blocks, 4 candidate-chunks), 256 threads.
// Block: 128 queries x 2048 candidates (16 tiles of 128), K = 64.
// Rank key: sq[j] - 2*dot(x_i, x_j)  (row-constant shift of reference dist).
// Partial top-20 per (query, chunk, half) -> 8 lists, merged later.
// LDS: Qs 32KB + Cs 16KB (k-split) + S 16KB = 64KB exactly.
// ---------------------------------------------------------------------------
template <int LDX>
__global__ __launch_bounds__(256) void knn_gemm_kernel(
    const float* __restrict__ x, const float* __restrict__ sq,
    float* __restrict__ pd, int* __restrict__ pj) {
  __shared__ float Qs[64 * 128];   // [k][m], col-swizzled
  __shared__ float Cs[32 * 128];   // [k2][n], col-swizzled (k half)
  __shared__ float S[128 * 32];    // [q][cc], cc-swizzled (quarter of tile)
  const int t = threadIdx.x;
  const int qb = blockIdx.x;       // 0..63
  const int ch = blockIdx.y;       // 0..3
  const int q0 = (t & 15) * 8;
  const int c0 = (t >> 4) * 8;

  // load Q tile (once): 128 rows x 64 k
  for (int r = 0; r < 8; ++r) {
    int lin = t + r * 256;         // 0..2047
    int m = lin >> 4, k4 = (lin & 15) * 4;
    const float4 v = *(const float4*)&x[(size_t)(qb * 128 + m) * LDX + k4];
    Qs[(k4 + 0) * 128 + (m ^ (((k4 + 0) & 31) << 2))] = v.x;
    Qs[(k4 + 1) * 128 + (m ^ (((k4 + 1) & 31) << 2))] = v.y;
    Qs[(k4 + 2) * 128 + (m ^ (((k4 + 2) & 31) << 2))] = v.z;
    Qs[(k4 + 3) * 128 + (m ^ (((k4 + 3) & 31) << 2))] = v.w;
  }

  const int selq = t & 127, part = t >> 7;
  const int gq_sel = qb * 128 + selq;
  float dreg[KNN]; int ireg[KNN];
#pragma unroll
  for (int r = 0; r < KNN; ++r) { dreg[r] = INFINITY; ireg[r] = 0x7fffffff; }

  for (int tile = 0; tile < 16; ++tile) {
    const int cb = ch * 2048 + tile * 128;
    float acc[8][8] = {};
    // two k-halves through Cs
    for (int kh = 0; kh < 2; ++kh) {
      __syncthreads();  // Cs free (prev k-loop / S phases done)
      for (int r = 0; r < 4; ++r) {
        int lin = t + r * 256;     // 0..1023 -> 128 n x 8 k4-slots
        int n = lin >> 3, k4 = (lin & 7) * 4;
        const float4 v =
            *(const float4*)&x[(size_t)(cb + n) * LDX + kh * 32 + k4];
        Cs[(k4 + 0) * 128 + (n ^ (((k4 + 0) & 31) << 2))] = v.x;
        Cs[(k4 + 1) * 128 + (n ^ (((k4 + 1) & 31) << 2))] = v.y;
        Cs[(k4 + 2) * 128 + (n ^ (((k4 + 2) & 31) << 2))] = v.z;
        Cs[(k4 + 3) * 128 + (n ^ (((k4 + 3) & 31) << 2))] = v.w;
      }
      __syncthreads();
#pragma unroll 8
      for (int k2 = 0; k2 < 32; ++k2) {
        const int k = kh * 32 + k2;
        const int s = (k & 31) << 2;
        const float* qa = &Qs[k * 128];
        const float* ca = &Cs[k2 * 128];
        float4 A0 = *(const float4*)&qa[q0 ^ s];
        float4 A1 = *(const float4*)&qa[(q0 + 4) ^ s];
        float4 B0 = *(const float4*)&ca[c0 ^ s];
        float4 B1 = *(const float4*)&ca[(c0 + 4) ^ s];
        float a[8] = {A0.x, A0.y, A0.z, A0.w, A1.x, A1.y, A1.z, A1.w};
        float b[8] = {B0.x, B0.y, B0.z, B0.w, B1.x, B1.y, B1.z, B1.w};
#pragma unroll
        for (int u = 0; u < 8; ++u)
#pragma unroll
          for (int v = 0; v < 8; ++v) acc[u][v] = fmaf(a[u], b[v], acc[u][v]);
      }
    }
    // sq for my 8 candidates
    float4 s0 = *(const float4*)&sq[cb + c0];
    float4 s1 = *(const float4*)&sq[cb + c0 + 4];
    float sc[8] = {s0.x, s0.y, s0.z, s0.w, s1.x, s1.y, s1.z, s1.w};

    for (int quarter = 0; quarter < 4; ++quarter) {
      __syncthreads();  // S free from previous sel
      if ((c0 >> 5) == quarter) {
        const int ccs = c0 & 31;
#pragma unroll
        for (int u = 0; u < 8; ++u) {
          const int gqv = qb * 128 + q0 + u;
          const int szw = (u & 7) << 2;  // (q0+u)&7 == u
          float w[8];
#pragma unroll
          for (int v = 0; v < 8; ++v) {
            int j = cb + c0 + v;
            float val = fmaf(-2.f, acc[u][v], sc[v]);
            w[v] = (j == gqv) ? INFINITY : val;
          }
          *(float4*)&S[(q0 + u) * 32 + (ccs ^ szw)] =
              make_float4(w[0], w[1], w[2], w[3]);
          *(float4*)&S[(q0 + u) * 32 + ((ccs + 4) ^ szw)] =
              make_float4(w[4], w[5], w[6], w[7]);
        }
      }
      __syncthreads();
      // selection: 16 candidates of this quarter per thread
      const int szr = (selq & 7) << 2;
      const int jb = cb + quarter * 32;
#pragma unroll 1
      for (int g = 0; g < 4; ++g) {
        const int cc = part * 16 + g * 4;
        float4 sv = *(const float4*)&S[selq * 32 + (cc ^ szr)];
        float vv[4] = {sv.x, sv.y, sv.z, sv.w};
#pragma unroll
        for (int e = 0; e < 4; ++e) {
          float val = vv[e];
          if (val < dreg[KNN - 1])
            insert20(dreg, ireg, val, jb + cc + e);
        }
      }
    }
  }
  // write partial list
  const int l = ch * 2 + part;
  float* pdq = pd + ((size_t)l * NPTS + gq_sel) * KNN;
  int* pjq = pj + ((size_t)l * NPTS + gq_sel) * KNN;
#pragma unroll
  for (int r = 0; r < KNN; ++r) { pdq[r] = dreg[r]; pjq[r] = ireg[r]; }
}

// ---------------------------------------------------------------------------
// 3-D kNN pass: thread-per-query streaming over LDS candidate tiles.
// Grid: (32 query-blocks, 8 chunks), 256 threads. 8 partial lists.
// ---------------------------------------------------------------------------
__global__ __launch_bounds__(256) void knn_d3_kernel(
    const float* __restrict__ x, const float* __restrict__ sq,
    float* __restrict__ pd, int* __restrict__ pj) {
  __shared__ float4 Ct[256];  // {x, y, z, sq}
  const int t = threadIdx.x;
  const int q = blockIdx.x * 256 + t;
  const int ch = blockIdx.y;
  const float xi0 = x[q * 3], xi1 = x[q * 3 + 1], xi2 = x[q * 3 + 2];
  float dreg[KNN]; int ireg[KNN];
#pragma unroll
  for (int r = 0; r < KNN; ++r) { dreg[r] = INFINITY; ireg[r] = 0x7fffffff; }

  for (int tile = 0; tile < 4; ++tile) {
    const int cb = ch * 1024 + tile * 256;
    __syncthreads();
    Ct[t] = make_float4(x[(cb + t) * 3], x[(cb + t) * 3 + 1],
                        x[(cb + t) * 3 + 2], sq[cb + t]);
    __syncthreads();
#pragma unroll 1
    for (int c = 0; c < 256; ++c) {
      float4 cv = Ct[c];
      int j = cb + c;
      float val = fmaf(-2.f, xi0 * cv.x + xi1 * cv.y + xi2 * cv.z, cv.w);
      if (j != q && val < dreg[KNN - 1]) insert20(dreg, ireg, val, j);
    }
  }
  float* pdq = pd + ((size_t)ch * NPTS + q) * KNN;
  int* pjq = pj + ((size_t)ch * NPTS + q) * KNN;
#pragma unroll
  for (int r = 0; r < KNN; ++r) { pdq[r] = dreg[r]; pjq[r] = ireg[r]; }
}

// ---------------------------------------------------------------------------
// merge 8 partial top-20 lists per query -> final 20 indices
// ---------------------------------------------------------------------------
__global__ __launch_bounds__(256) void knn_merge_kernel(
    const float* __restrict__ pd, const int* __restrict__ pj,
    int* __restrict__ idx_out) {
  const int q = blockIdx.x * 256 + threadIdx.x;
  float d[KNN]; int ix[KNN];
#pragma unroll
  for (int r = 0; r < KNN; ++r) { d[r] = INFINITY; ix[r] = 0x7fffffff; }
#pragma unroll 1
  for (int l = 0; l < 8; ++l) {
    const float* pdq = pd + ((size_t)l * NPTS + q) * KNN;
    const int* pjq = pj + ((size_t)l * NPTS + q) * KNN;
#pragma unroll 1
    for (int r = 0; r < KNN; ++r) {
      float val = pdq[r]; int j = pjq[r];
      bool worse = (val > d[KNN - 1]) ||
                   (val == d[KNN - 1] && j > ix[KNN - 1]);
      if (!worse) insert20t(d, ix, val, j);
    }
  }
#pragma unroll
  for (int r = 0; r < KNN; ++r) idx_out[(size_t)q * KNN + r] = ix[r];
}

// ---------------------------------------------------------------------------
// edge conv: out[i][c] = max_k relu(b + [x_i, x_j-x_i] . W1[:,c])
// ---------------------------------------------------------------------------
__global__ __launch_bounds__(64) void edgeconv_kernel(
    const float* __restrict__ x, const int* __restrict__ idx,
    const float* __restrict__ W1, const float* __restrict__ b1,
    float* __restrict__ out) {
  const int i = blockIdx.x;
  const int c = threadIdx.x;
  float w0 = W1[c], w1 = W1[64 + c], w2 = W1[128 + c];
  float w3 = W1[192 + c], w4 = W1[256 + c], w5 = W1[320 + c];
  float xi0 = x[3 * i], xi1 = x[3 * i + 1], xi2 = x[3 * i + 2];
  float base = b1[c] + xi0 * w0 + xi1 * w1 + xi2 * w2;
  float m = -INFINITY;
#pragma unroll
  for (int k = 0; k < KNN; ++k) {
    int j = idx[i * KNN + k];
    float d0 = x[3 * j] - xi0, d1 = x[3 * j + 1] - xi1, d2 = x[3 * j + 2] - xi2;
    float h = base + d0 * w3 + d1 * w4 + d2 * w5;
    m = fmaxf(m, fmaxf(h, 0.f));
  }
  out[(size_t)i * 64 + c] = m;
}

// ---------------------------------------------------------------------------
// dilate: dil[c] = max_k xin[idx[k]][c]; out = relu(dil.W + b) - xin
// ---------------------------------------------------------------------------
__global__ __launch_bounds__(64) void dilate_kernel(
    const float* __restrict__ xin, int ldin, const int* __restrict__ idx,
    const float* __restrict__ W, const float* __restrict__ bias,
    float* __restrict__ out, int ldout) {
  const int i = blockIdx.x;
  const int c = threadIdx.x;
  __shared__ float dil[64];
  float m = -INFINITY;
#pragma unroll
  for (int k = 0; k < KNN; ++k) {
    int j = idx[i * KNN + k];
    m = fmaxf(m, xin[(size_t)j * ldin + c]);
  }
  dil[c] = m;
  __syncthreads();
  float acc = bias[c];
#pragma unroll
  for (int d = 0; d < 64; ++d) acc = fmaf(dil[d], W[d * 64 + c], acc);
  out[(size_t)i * ldout + c] = fmaxf(acc, 0.f) - xin[(size_t)i * ldin + c];
}

// ---------------------------------------------------------------------------
// C[M x N] = (relu?) (A[M x K] @ W[K x N] + bias). BM=BN=64, BK=16, 256 thr.
// ---------------------------------------------------------------------------
__global__ __launch_bounds__(256) void gemm_relu_kernel(
    const float* __restrict__ A, int K, int ldA, const float* __restrict__ W,
    int N, const float* __restrict__ bias, float* __restrict__ C, int ldC,
    int relu) {
  __shared__ float As[16][68];
  __shared__ float Bs[16][64];
  const int bn = blockIdx.x * 64;
  const int bm = blockIdx.y * 64;
  const int tid = threadIdx.x;
  const int tx = tid & 15, ty = tid >> 4;
  float acc[4][4] = {};
  for (int k0 = 0; k0 < K; k0 += 16) {
#pragma unroll
    for (int l = tid; l < 1024; l += 256) {
      int m = l >> 4, k = l & 15;
      As[k][m] = A[(size_t)(bm + m) * ldA + k0 + k];
    }
#pragma unroll
    for (int l = tid; l < 1024; l += 256) {
      int n = l & 63, k = l >> 6;
      Bs[k][n] = W[(size_t)(k0 + k) * N + bn + n];
    }
    __syncthreads();
#pragma unroll
    for (int k = 0; k < 16; ++k) {
      float4 av = *(const float4*)&As[k][ty * 4];
      float4 bv = *(const float4*)&Bs[k][tx * 4];
      float a[4] = {av.x, av.y, av.z, av.w};
      float b[4] = {bv.x, bv.y, bv.z, bv.w};
#pragma unroll
      for (int u = 0; u < 4; ++u)
#pragma unroll
        for (int v = 0; v < 4; ++v) acc[u][v] = fmaf(a[u], b[v], acc[u][v]);
    }
    __syncthreads();
  }
#pragma unroll
  for (int u = 0; u < 4; ++u) {
    int m = bm + ty * 4 + u;
#pragma unroll
    for (int v = 0; v < 4; ++v) {
      int n = bn + tx * 4 + v;
      float val = acc[u][v] + bias[n];
      if (relu) val = fmaxf(val, 0.f);
      C[(size_t)m * ldC + n] = val;
    }
  }
}

// ---------------------------------------------------------------------------
// logits = h3 @ Wm3 + bm3 ; out = log_softmax(logits)
// ---------------------------------------------------------------------------
__global__ __launch_bounds__(256) void final_kernel(
    const float* __restrict__ h3, const float* __restrict__ Wm3,
    const float* __restrict__ bm3, float* __restrict__ out) {
  __shared__ float hs[16][132];
  const int tid = threadIdx.x;
  const int r = tid >> 4, c = tid & 15;
  const int row0 = blockIdx.x * 16;
#pragma unroll
  for (int l = tid; l < 2048; l += 256)
    hs[l >> 7][l & 127] = h3[(size_t)row0 * 128 + l];
  __syncthreads();
  float acc = bm3[c];
#pragma unroll
  for (int d = 0; d < 128; ++d) acc = fmaf(hs[r][d], Wm3[d * 16 + c], acc);
  float mx = acc;
#pragma unroll
  for (int o = 8; o >= 1; o >>= 1) mx = fmaxf(mx, __shfl_xor(mx, o, 16));
  float e = expf(acc - mx);
  float s = e;
#pragma unroll
  for (int o = 8; o >= 1; o >>= 1) s += __shfl_xor(s, o, 16);
  out[(size_t)(row0 + r) * 16 + c] = (acc - mx) - logf(s);
}

// ---------------------------------------------------------------------------
extern "C" void kernel_launch(void* const* d_in, const int* in_sizes, int n_in,
                              void* d_out, int out_size, void* d_ws,
                              size_t ws_size, hipStream_t stream) {
  const float* x = (const float*)d_in[0];
  const float* W1 = (const float*)d_in[1];
  const float* b1 = (const float*)d_in[2];
  const float* Wd1 = (const float*)d_in[3];
  const float* bd1 = (const float*)d_in[4];
  const float* Wd2 = (const float*)d_in[5];
  const float* bd2 = (const float*)d_in[6];
  const float* Wd3 = (const float*)d_in[7];
  const float* bd3 = (const float*)d_in[8];
  const float* Wl = (const float*)d_in[9];
  const float* bl = (const float*)d_in[10];
  const float* Wm1 = (const float*)d_in[11];
  const float* bm1 = (const float*)d_in[12];
  const float* Wm2 = (const float*)d_in[13];
  const float* bm2 = (const float*)d_in[14];
  const float* Wm3 = (const float*)d_in[15];
  const float* bm3 = (const float*)d_in[16];
  float* out = (float*)d_out;

  char* ws = (char*)d_ws;
  float* sq = (float*)(ws + 0);              // 32 KB
  int* idxA = (int*)(ws + 32768);            // 640 KB
  float* xfeat = (float*)(ws + 1343488);     // 2 MB   [8192 x 64]
  float* xcat = (float*)(ws + 3440640);      // 6 MB   [8192 x 192]
  float* h1 = (float*)(ws + 9732096);        // 32 MB  [8192 x 1024]
  float* h2 = (float*)(ws + 43286528);       // 8 MB   [8192 x 256]
  float* h3 = (float*)(ws + 51675136);       // 4 MB   [8192 x 128]
  float* x1 = xcat;
  float* x2 = xcat + 64;
  float* x3 = xcat + 128;
  // partial knn lists live in the (not-yet-used) h1 region
  float* pd = h1;                            // 5.24 MB
  int* pj = (int*)(h1 + 8 * NPTS * KNN);     // 5.24 MB

  // stage 1: edge conv on xyz
  sqnorm_kernel<<<32, 256, 0, stream>>>(x, 3, 3, sq);
  knn_d3_kernel<<<dim3(32, 8), 256, 0, stream>>>(x, sq, pd, pj);
  knn_merge_kernel<<<32, 256, 0, stream>>>(pd, pj, idxA);
  edgeconv_kernel<<<NPTS, 64, 0, stream>>>(x, idxA, W1, b1, xfeat);

  // stage 2: three dilate blocks (kNN in 64-D feature space each)
  sqnorm_kernel<<<32, 256, 0, stream>>>(xfeat, 64, 64, sq);
  knn_gemm_kernel<64><<<dim3(64, 4), 256, 0, stream>>>(xfeat, sq, pd, pj);
  knn_merge_kernel<<<32, 256, 0, stream>>>(pd, pj, idxA);
  dilate_kernel<<<NPTS, 64, 0, stream>>>(xfeat, 64, idxA, Wd1, bd1, x1, 192);

  sqnorm_kernel<<<32, 256, 0, stream>>>(x1, 192, 64, sq);
  knn_gemm_kernel<192><<<dim3(64, 4), 256, 0, stream>>>(x1, sq, pd, pj);
  knn_merge_kernel<<<32, 256, 0, stream>>>(pd, pj, idxA);
  dilate_kernel<<<NPTS, 64, 0, stream>>>(x1, 192, idxA, Wd2, bd2, x2, 192);

  sqnorm_kernel<<<32, 256, 0, stream>>>(x2, 192, 64, sq);
  knn_gemm_kernel<192><<<dim3(64, 4), 256, 0, stream>>>(x2, sq, pd, pj);
  knn_merge_kernel<<<32, 256, 0, stream>>>(pd, pj, idxA);
  dilate_kernel<<<NPTS, 64, 0, stream>>>(x2, 192, idxA, Wd3, bd3, x3, 192);

  // stage 3: MLP head
  gemm_relu_kernel<<<dim3(1024 / 64, NPTS / 64), 256, 0, stream>>>(
      xcat, 192, 192, Wl, 1024, bl, h1, 1024, 1);
  gemm_relu_kernel<<<dim3(256 / 64, NPTS / 64), 256, 0, stream>>>(
      h1, 1024, 1024, Wm1, 256, bm1, h2, 256, 1);
  gemm_relu_kernel<<<dim3(128 / 64, NPTS / 64), 256, 0, stream>>>(
      h2, 256, 256, Wm2, 128, bm2, h3, 128, 1);
  final_kernel<<<NPTS / 16, 256, 0, stream>>>(h3, Wm3, bm3, out);
}

// Round 3
// 3032.206 us; speedup vs baseline: 10.6565x; 1.1425x over previous
//
#include <hip/hip_runtime.h>
#include <math.h>

#define NPTS 8192
#define KNN 20

// ---------------------------------------------------------------------------
// sq[i] = sum_d x[i][d]^2
// ---------------------------------------------------------------------------
__global__ void sqnorm_kernel(const float* __restrict__ x, int ldx, int D,
                              float* __restrict__ sq) {
  int i = blockIdx.x * blockDim.x + threadIdx.x;
  if (i >= NPTS) return;
  const float* xr = x + (size_t)i * ldx;
  float s = 0.f;
  for (int d = 0; d < D; ++d) { float v = xr[d]; s += v * v; }
  sq[i] = s;
}

// ---------------------------------------------------------------------------
// Branchless sorted-insert (ascending). Caller guards with val < d[19].
// Strict < keeps earlier-scanned (smaller j) entries ahead on ties.
// ---------------------------------------------------------------------------
__device__ __forceinline__ void insert20(float (&d)[KNN], int (&ix)[KNN],
                                         float val, int j) {
  float cv = val; int ci = j;
#pragma unroll
  for (int r = 0; r < KNN; ++r) {
    bool sw = cv < d[r];
    float od = d[r]; int oi = ix[r];
    d[r] = sw ? cv : od; ix[r] = sw ? ci : oi;
    cv = sw ? od : cv;  ci = sw ? oi : ci;
  }
}

// tie-aware version for the merge (dist, then index)
__device__ __forceinline__ void insert20t(float (&d)[KNN], int (&ix)[KNN],
                                          float val, int j) {
  float cv = val; int ci = j;
#pragma unroll
  for (int r = 0; r < KNN; ++r) {
    bool sw = (cv < d[r]) || (cv == d[r] && ci < ix[r]);
    float od = d[r]; int oi = ix[r];
    d[r] = sw ? cv : od; ix[r] = sw ? ci : oi;
    cv = sw ? od : cv;  ci = sw ? oi : ci;
  }
}

// ---------------------------------------------------------------------------
// 64-D kNN pass: fused fp32 GEMM + top-20 selection.
// Grid: (64 query-blocks, 8 candidate-chunks), 256 threads, 64 KB LDS
// -> 2 blocks/CU. Block: 128 queries x 1024 candidates (8 tiles of 128),
// K = 64 (two k-halves of 32 through Cs).
// Rank key: sq[j] - 2*dot(x_i, x_j) (row-constant shift of reference dist).
// Fragment map: thread (am = t&15, bg = (t>>4)&15) owns queries
// {4am..4am+3, 64+4am..+3} x cands {4bg..4bg+3, 64+4bg..+3}:
//  - A ds_read_b128: each octet of lanes covers 8 distinct bank-slots (free)
//  - B ds_read_b128: wave-broadcast (free)
// Score LDS swizzle g(row)=((row&7)^((row>>2)&7))<<2 is conflict-free for
// both the stride-4-row writes and stride-1-row reads (per-octet bijection).
// ---------------------------------------------------------------------------
template <int LDX>
__global__ __launch_bounds__(256) void knn_gemm_kernel(
    const float* __restrict__ x, const float* __restrict__ sq,
    float* __restrict__ pd, int* __restrict__ pj) {
  __shared__ float Qs[64 * 128];  // [k][q]
  __shared__ float Cs[32 * 128];  // [k2][n]  (k half)
  __shared__ float S[128 * 32];   // [q][cc ^ g(q)]
  const int t = threadIdx.x;
  const int qb = blockIdx.x;  // 0..63
  const int ch = blockIdx.y;  // 0..7
  const int am = t & 15;
  const int bg = (t >> 4) & 15;

  // stage Q tile once: thread handles q = t&127, k-half (t>>7)*32
  {
    const int q = t & 127;
    const int k0 = (t >> 7) * 32;
    const float* src = &x[(size_t)(qb * 128 + q) * LDX + k0];
#pragma unroll
    for (int c = 0; c < 8; ++c) {
      float4 v = *(const float4*)&src[c * 4];
      Qs[(k0 + c * 4 + 0) * 128 + q] = v.x;
      Qs[(k0 + c * 4 + 1) * 128 + q] = v.y;
      Qs[(k0 + c * 4 + 2) * 128 + q] = v.z;
      Qs[(k0 + c * 4 + 3) * 128 + q] = v.w;
    }
  }

  const int selq = t & 127, part = t >> 7;
  float dreg[KNN]; int ireg[KNN];
#pragma unroll
  for (int r = 0; r < KNN; ++r) { dreg[r] = INFINITY; ireg[r] = 0x7fffffff; }

  for (int tile = 0; tile < 8; ++tile) {
    const int cb = ch * 1024 + tile * 128;
    float acc[8][8] = {};
    for (int kh = 0; kh < 2; ++kh) {
      __syncthreads();  // Cs free (prev compute / prev S phase done)
      {
        const int n = t & 127;
        const int k0 = (t >> 7) * 16;
        const float* src = &x[(size_t)(cb + n) * LDX + kh * 32 + k0];
#pragma unroll
        for (int c = 0; c < 4; ++c) {
          float4 v = *(const float4*)&src[c * 4];
          Cs[(k0 + c * 4 + 0) * 128 + n] = v.x;
          Cs[(k0 + c * 4 + 1) * 128 + n] = v.y;
          Cs[(k0 + c * 4 + 2) * 128 + n] = v.z;
          Cs[(k0 + c * 4 + 3) * 128 + n] = v.w;
        }
      }
      __syncthreads();
#pragma unroll 4
      for (int k2 = 0; k2 < 32; ++k2) {
        const int k = kh * 32 + k2;
        float4 A0 = *(const float4*)&Qs[k * 128 + 4 * am];
        float4 A1 = *(const float4*)&Qs[k * 128 + 4 * am + 64];
        float4 B0 = *(const float4*)&Cs[k2 * 128 + 4 * bg];
        float4 B1 = *(const float4*)&Cs[k2 * 128 + 4 * bg + 64];
        float a[8] = {A0.x, A0.y, A0.z, A0.w, A1.x, A1.y, A1.z, A1.w};
        float b[8] = {B0.x, B0.y, B0.z, B0.w, B1.x, B1.y, B1.z, B1.w};
#pragma unroll
        for (int u = 0; u < 8; ++u)
#pragma unroll
          for (int v = 0; v < 8; ++v) acc[u][v] = fmaf(a[u], b[v], acc[u][v]);
      }
    }
    // sq for my 8 candidates
    float4 s0 = *(const float4*)&sq[cb + 4 * bg];
    float4 s1 = *(const float4*)&sq[cb + 4 * bg + 64];
    float sc[8] = {s0.x, s0.y, s0.z, s0.w, s1.x, s1.y, s1.z, s1.w};

    for (int qr = 0; qr < 4; ++qr) {
      __syncthreads();  // S free from previous phase
      int grp = (qr == (bg >> 3)) ? 0 : (qr == 2 + (bg >> 3)) ? 1 : -1;
      if (grp >= 0) {
        const int cc = (4 * bg) & 31;
#pragma unroll
        for (int u = 0; u < 8; ++u) {
          const int row = 4 * am + (u & 3) + 64 * (u >> 2);
          const int gq = qb * 128 + row;
          const int sw = ((row & 7) ^ ((row >> 2) & 7)) << 2;
          float w[4];
#pragma unroll
          for (int e = 0; e < 4; ++e) {
            const int v = grp * 4 + e;
            const int j = cb + qr * 32 + cc + e;
            float val = fmaf(-2.f, acc[u][v], sc[v]);
            w[e] = (j == gq) ? INFINITY : val;
          }
          *(float4*)&S[row * 32 + (cc ^ sw)] =
              make_float4(w[0], w[1], w[2], w[3]);
        }
      }
      __syncthreads();
      const int swr = ((selq & 7) ^ ((selq >> 2) & 7)) << 2;
      const int jb = cb + qr * 32;
#pragma unroll
      for (int g_ = 0; g_ < 4; ++g_) {
        const int cc = part * 16 + g_ * 4;
        float4 sv = *(const float4*)&S[selq * 32 + (cc ^ swr)];
        float vv[4] = {sv.x, sv.y, sv.z, sv.w};
#pragma unroll
        for (int e = 0; e < 4; ++e) {
          if (vv[e] < dreg[KNN - 1]) insert20(dreg, ireg, vv[e], jb + cc + e);
        }
      }
    }
  }
  // write partial list (16 lists: ch*2 + part)
  const int l = ch * 2 + part;
  float* pdq = pd + ((size_t)l * NPTS + (qb * 128 + selq)) * KNN;
  int* pjq = pj + ((size_t)l * NPTS + (qb * 128 + selq)) * KNN;
#pragma unroll
  for (int r = 0; r < KNN; ++r) { pdq[r] = dreg[r]; pjq[r] = ireg[r]; }
}

// ---------------------------------------------------------------------------
// 3-D kNN pass: thread-per-query streaming over LDS candidate tiles.
// Grid: (32 query-blocks, 8 chunks), 256 threads. 8 partial lists.
// ---------------------------------------------------------------------------
__global__ __launch_bounds__(256) void knn_d3_kernel(
    const float* __restrict__ x, const float* __restrict__ sq,
    float* __restrict__ pd, int* __restrict__ pj) {
  __shared__ float4 Ct[256];  // {x, y, z, sq}
  const int t = threadIdx.x;
  const int q = blockIdx.x * 256 + t;
  const int ch = blockIdx.y;
  const float xi0 = x[q * 3], xi1 = x[q * 3 + 1], xi2 = x[q * 3 + 2];
  float dreg[KNN]; int ireg[KNN];
#pragma unroll
  for (int r = 0; r < KNN; ++r) { dreg[r] = INFINITY; ireg[r] = 0x7fffffff; }

  for (int tile = 0; tile < 4; ++tile) {
    const int cb = ch * 1024 + tile * 256;
    __syncthreads();
    Ct[t] = make_float4(x[(cb + t) * 3], x[(cb + t) * 3 + 1],
                        x[(cb + t) * 3 + 2], sq[cb + t]);
    __syncthreads();
#pragma unroll 1
    for (int c = 0; c < 256; ++c) {
      float4 cv = Ct[c];
      int j = cb + c;
      float val = fmaf(-2.f, xi0 * cv.x + xi1 * cv.y + xi2 * cv.z, cv.w);
      if (j != q && val < dreg[KNN - 1]) insert20(dreg, ireg, val, j);
    }
  }
  float* pdq = pd + ((size_t)ch * NPTS + q) * KNN;
  int* pjq = pj + ((size_t)ch * NPTS + q) * KNN;
#pragma unroll
  for (int r = 0; r < KNN; ++r) { pdq[r] = dreg[r]; pjq[r] = ireg[r]; }
}

// ---------------------------------------------------------------------------
// merge L partial top-20 lists per query -> final 20 indices
// ---------------------------------------------------------------------------
__global__ __launch_bounds__(128) void knn_merge_kernel(
    const float* __restrict__ pd, const int* __restrict__ pj,
    int* __restrict__ idx_out, int L) {
  const int q = blockIdx.x * 128 + threadIdx.x;
  float d[KNN]; int ix[KNN];
#pragma unroll
  for (int r = 0; r < KNN; ++r) { d[r] = INFINITY; ix[r] = 0x7fffffff; }
#pragma unroll 1
  for (int l = 0; l < L; ++l) {
    const float* pdq = pd + ((size_t)l * NPTS + q) * KNN;
    const int* pjq = pj + ((size_t)l * NPTS + q) * KNN;
#pragma unroll 1
    for (int r = 0; r < KNN; ++r) {
      float val = pdq[r]; int j = pjq[r];
      bool worse = (val > d[KNN - 1]) ||
                   (val == d[KNN - 1] && j > ix[KNN - 1]);
      if (!worse) insert20t(d, ix, val, j);
    }
  }
#pragma unroll
  for (int r = 0; r < KNN; ++r) idx_out[(size_t)q * KNN + r] = ix[r];
}

// ---------------------------------------------------------------------------
// edge conv: out[i][c] = max_k relu(b + [x_i, x_j-x_i] . W1[:,c])
// ---------------------------------------------------------------------------
__global__ __launch_bounds__(64) void edgeconv_kernel(
    const float* __restrict__ x, const int* __restrict__ idx,
    const float* __restrict__ W1, const float* __restrict__ b1,
    float* __restrict__ out) {
  const int i = blockIdx.x;
  const int c = threadIdx.x;
  float w0 = W1[c], w1 = W1[64 + c], w2 = W1[128 + c];
  float w3 = W1[192 + c], w4 = W1[256 + c], w5 = W1[320 + c];
  float xi0 = x[3 * i], xi1 = x[3 * i + 1], xi2 = x[3 * i + 2];
  float base = b1[c] + xi0 * w0 + xi1 * w1 + xi2 * w2;
  float m = -INFINITY;
#pragma unroll
  for (int k = 0; k < KNN; ++k) {
    int j = idx[i * KNN + k];
    float d0 = x[3 * j] - xi0, d1 = x[3 * j + 1] - xi1, d2 = x[3 * j + 2] - xi2;
    float h = base + d0 * w3 + d1 * w4 + d2 * w5;
    m = fmaxf(m, fmaxf(h, 0.f));
  }
  out[(size_t)i * 64 + c] = m;
}

// ---------------------------------------------------------------------------
// dilate: dil[c] = max_k xin[idx[k]][c]; out = relu(dil.W + b) - xin
// ---------------------------------------------------------------------------
__global__ __launch_bounds__(64) void dilate_kernel(
    const float* __restrict__ xin, int ldin, const int* __restrict__ idx,
    const float* __restrict__ W, const float* __restrict__ bias,
    float* __restrict__ out, int ldout) {
  const int i = blockIdx.x;
  const int c = threadIdx.x;
  __shared__ float dil[64];
  float m = -INFINITY;
#pragma unroll
  for (int k = 0; k < KNN; ++k) {
    int j = idx[i * KNN + k];
    m = fmaxf(m, xin[(size_t)j * ldin + c]);
  }
  dil[c] = m;
  __syncthreads();
  float acc = bias[c];
#pragma unroll
  for (int d = 0; d < 64; ++d) acc = fmaf(dil[d], W[d * 64 + c], acc);
  out[(size_t)i * ldout + c] = fmaxf(acc, 0.f) - xin[(size_t)i * ldin + c];
}

// ---------------------------------------------------------------------------
// C[M x N] = (relu?) (A[M x K] @ W[K x N] + bias). BM=BN=64, BK=16, 256 thr.
// ---------------------------------------------------------------------------
__global__ __launch_bounds__(256) void gemm_relu_kernel(
    const float* __restrict__ A, int K, int ldA, const float* __restrict__ W,
    int N, const float* __restrict__ bias, float* __restrict__ C, int ldC,
    int relu) {
  __shared__ float As[16][68];
  __shared__ float Bs[16][64];
  const int bn = blockIdx.x * 64;
  const int bm = blockIdx.y * 64;
  const int tid = threadIdx.x;
  const int tx = tid & 15, ty = tid >> 4;
  float acc[4][4] = {};
  for (int k0 = 0; k0 < K; k0 += 16) {
#pragma unroll
    for (int l = tid; l < 1024; l += 256) {
      int m = l >> 4, k = l & 15;
      As[k][m] = A[(size_t)(bm + m) * ldA + k0 + k];
    }
#pragma unroll
    for (int l = tid; l < 1024; l += 256) {
      int n = l & 63, k = l >> 6;
      Bs[k][n] = W[(size_t)(k0 + k) * N + bn + n];
    }
    __syncthreads();
#pragma unroll
    for (int k = 0; k < 16; ++k) {
      float4 av = *(const float4*)&As[k][ty * 4];
      float4 bv = *(const float4*)&Bs[k][tx * 4];
      float a[4] = {av.x, av.y, av.z, av.w};
      float b[4] = {bv.x, bv.y, bv.z, bv.w};
#pragma unroll
      for (int u = 0; u < 4; ++u)
#pragma unroll
        for (int v = 0; v < 4; ++v) acc[u][v] = fmaf(a[u], b[v], acc[u][v]);
    }
    __syncthreads();
  }
#pragma unroll
  for (int u = 0; u < 4; ++u) {
    int m = bm + ty * 4 + u;
#pragma unroll
    for (int v = 0; v < 4; ++v) {
      int n = bn + tx * 4 + v;
      float val = acc[u][v] + bias[n];
      if (relu) val = fmaxf(val, 0.f);
      C[(size_t)m * ldC + n] = val;
    }
  }
}

// ---------------------------------------------------------------------------
// logits = h3 @ Wm3 + bm3 ; out = log_softmax(logits)
// ---------------------------------------------------------------------------
__global__ __launch_bounds__(256) void final_kernel(
    const float* __restrict__ h3, const float* __restrict__ Wm3,
    const float* __restrict__ bm3, float* __restrict__ out) {
  __shared__ float hs[16][132];
  const int tid = threadIdx.x;
  const int r = tid >> 4, c = tid & 15;
  const int row0 = blockIdx.x * 16;
#pragma unroll
  for (int l = tid; l < 2048; l += 256)
    hs[l >> 7][l & 127] = h3[(size_t)row0 * 128 + l];
  __syncthreads();
  float acc = bm3[c];
#pragma unroll
  for (int d = 0; d < 128; ++d) acc = fmaf(hs[r][d], Wm3[d * 16 + c], acc);
  float mx = acc;
#pragma unroll
  for (int o = 8; o >= 1; o >>= 1) mx = fmaxf(mx, __shfl_xor(mx, o, 16));
  float e = expf(acc - mx);
  float s = e;
#pragma unroll
  for (int o = 8; o >= 1; o >>= 1) s += __shfl_xor(s, o, 16);
  out[(size_t)(row0 + r) * 16 + c] = (acc - mx) - logf(s);
}

// ---------------------------------------------------------------------------
extern "C" void kernel_launch(void* const* d_in, const int* in_sizes, int n_in,
                              void* d_out, int out_size, void* d_ws,
                              size_t ws_size, hipStream_t stream) {
  const float* x = (const float*)d_in[0];
  const float* W1 = (const float*)d_in[1];
  const float* b1 = (const float*)d_in[2];
  const float* Wd1 = (const float*)d_in[3];
  const float* bd1 = (const float*)d_in[4];
  const float* Wd2 = (const float*)d_in[5];
  const float* bd2 = (const float*)d_in[6];
  const float* Wd3 = (const float*)d_in[7];
  const float* bd3 = (const float*)d_in[8];
  const float* Wl = (const float*)d_in[9];
  const float* bl = (const float*)d_in[10];
  const float* Wm1 = (const float*)d_in[11];
  const float* bm1 = (const float*)d_in[12];
  const float* Wm2 = (const float*)d_in[13];
  const float* bm2 = (const float*)d_in[14];
  const float* Wm3 = (const float*)d_in[15];
  const float* bm3 = (const float*)d_in[16];
  float* out = (float*)d_out;

  char* ws = (char*)d_ws;
  float* sq = (float*)(ws + 0);              // 32 KB
  int* idxA = (int*)(ws + 32768);            // 640 KB
  float* xfeat = (float*)(ws + 1343488);     // 2 MB   [8192 x 64]
  float* xcat = (float*)(ws + 3440640);      // 6 MB   [8192 x 192]
  float* h1 = (float*)(ws + 9732096);        // 32 MB  [8192 x 1024]
  float* h2 = (float*)(ws + 43286528);       // 8 MB   [8192 x 256]
  float* h3 = (float*)(ws + 51675136);       // 4 MB   [8192 x 128]
  float* x1 = xcat;
  float* x2 = xcat + 64;
  float* x3 = xcat + 128;
  // partial knn lists live in the (not-yet-used) h1 region: 16 lists
  float* pd = h1;                            // 10.5 MB
  int* pj = (int*)(h1 + 16 * NPTS * KNN);    // 10.5 MB

  // stage 1: edge conv on xyz
  sqnorm_kernel<<<32, 256, 0, stream>>>(x, 3, 3, sq);
  knn_d3_kernel<<<dim3(32, 8), 256, 0, stream>>>(x, sq, pd, pj);
  knn_merge_kernel<<<64, 128, 0, stream>>>(pd, pj, idxA, 8);
  edgeconv_kernel<<<NPTS, 64, 0, stream>>>(x, idxA, W1, b1, xfeat);

  // stage 2: three dilate blocks (kNN in 64-D feature space each)
  sqnorm_kernel<<<32, 256, 0, stream>>>(xfeat, 64, 64, sq);
  knn_gemm_kernel<64><<<dim3(64, 8), 256, 0, stream>>>(xfeat, sq, pd, pj);
  knn_merge_kernel<<<64, 128, 0, stream>>>(pd, pj, idxA, 16);
  dilate_kernel<<<NPTS, 64, 0, stream>>>(xfeat, 64, idxA, Wd1, bd1, x1, 192);

  sqnorm_kernel<<<32, 256, 0, stream>>>(x1, 192, 64, sq);
  knn_gemm_kernel<192><<<dim3(64, 8), 256, 0, stream>>>(x1, sq, pd, pj);
  knn_merge_kernel<<<64, 128, 0, stream>>>(pd, pj, idxA, 16);
  dilate_kernel<<<NPTS, 64, 0, stream>>>(x1, 192, idxA, Wd2, bd2, x2, 192);

  sqnorm_kernel<<<32, 256, 0, stream>>>(x2, 192, 64, sq);
  knn_gemm_kernel<192><<<dim3(64, 8), 256, 0, stream>>>(x2, sq, pd, pj);
  knn_merge_kernel<<<64, 128, 0, stream>>>(pd, pj, idxA, 16);
  dilate_kernel<<<NPTS, 64, 0, stream>>>(x2, 192, idxA, Wd3, bd3, x3, 192);

  // stage 3: MLP head
  gemm_relu_kernel<<<dim3(1024 / 64, NPTS / 64), 256, 0, stream>>>(
      xcat, 192, 192, Wl, 1024, bl, h1, 1024, 1);
  gemm_relu_kernel<<<dim3(256 / 64, NPTS / 64), 256, 0, stream>>>(
      h1, 1024, 1024, Wm1, 256, bm1, h2, 256, 1);
  gemm_relu_kernel<<<dim3(128 / 64, NPTS / 64), 256, 0, stream>>>(
      h2, 256, 256, Wm2, 128, bm2, h3, 128, 1);
  final_kernel<<<NPTS / 16, 256, 0, stream>>>(h3, Wm3, bm3, out);
}

// Round 4
// 3028.567 us; speedup vs baseline: 10.6693x; 1.0012x over previous
//
#include <hip/hip_runtime.h>
#include <math.h>

#define NPTS 8192
#define KNN 20

// ---------------------------------------------------------------------------
// sq[i] = sum_d x[i][d]^2
// ---------------------------------------------------------------------------
__global__ void sqnorm_kernel(const float* __restrict__ x, int ldx, int D,
                              float* __restrict__ sq) {
  int i = blockIdx.x * blockDim.x + threadIdx.x;
  if (i >= NPTS) return;
  const float* xr = x + (size_t)i * ldx;
  float s = 0.f;
  for (int d = 0; d < D; ++d) { float v = xr[d]; s += v * v; }
  sq[i] = s;
}

// ---------------------------------------------------------------------------
// Branchless sorted-insert (ascending). Caller guards with val < d[19].
// Strict < keeps earlier-scanned (smaller j) entries ahead on ties.
// ---------------------------------------------------------------------------
__device__ __forceinline__ void insert20(float (&d)[KNN], int (&ix)[KNN],
                                         float val, int j) {
  float cv = val; int ci = j;
#pragma unroll
  for (int r = 0; r < KNN; ++r) {
    bool sw = cv < d[r];
    float od = d[r]; int oi = ix[r];
    d[r] = sw ? cv : od; ix[r] = sw ? ci : oi;
    cv = sw ? od : cv;  ci = sw ? oi : ci;
  }
}

// tie-aware version for the merge (dist, then index)
__device__ __forceinline__ void insert20t(float (&d)[KNN], int (&ix)[KNN],
                                          float val, int j) {
  float cv = val; int ci = j;
#pragma unroll
  for (int r = 0; r < KNN; ++r) {
    bool sw = (cv < d[r]) || (cv == d[r] && ci < ix[r]);
    float od = d[r]; int oi = ix[r];
    d[r] = sw ? cv : od; ix[r] = sw ? ci : oi;
    cv = sw ? od : cv;  ci = sw ? oi : ci;
  }
}

// ---------------------------------------------------------------------------
// 64-D kNN pass: fused fp32 GEMM + top-20 selection.
// Grid: (64 query-blocks, 8 candidate-chunks), 256 threads.
// __launch_bounds__(256,2): VGPR cap 256 -> no spill of dreg/ireg/acc
// (round-3 profile: VGPR capped at 108 => 618 MB scratch writes/dispatch).
// LDS 48 KB (Cs and S union -- never live at once; the kh-loop's leading
// barrier orders last S-reads before the Cs overwrite).
// Fragment map: thread (am = t&15, bg = (t>>4)&15) owns queries
// {4am..4am+3, 64+4am..+3} x cands {4bg..4bg+3, 64+4bg..+3}:
// A-reads 16 distinct b128 slots/octet + broadcast, B-reads broadcast (free).
// Score swizzle g(row)=((row&7)^((row>>2)&7))<<2: conflict-free write+read.
// ---------------------------------------------------------------------------
template <int LDX>
__global__ __launch_bounds__(256, 2) void knn_gemm_kernel(
    const float* __restrict__ x, const float* __restrict__ sq,
    float* __restrict__ pd, int* __restrict__ pj) {
  __shared__ float Qs[64 * 128];   // [k][q]
  __shared__ float CsS[32 * 128];  // Cs: [k2][n] during compute; S: [q][cc]
  float* const Cs = CsS;
  float* const S = CsS;
  const int t = threadIdx.x;
  const int qb = blockIdx.x;  // 0..63
  const int ch = blockIdx.y;  // 0..7
  const int am = t & 15;
  const int bg = (t >> 4) & 15;

  // stage Q tile once: thread handles q = t&127, k-half (t>>7)*32
  {
    const int q = t & 127;
    const int k0 = (t >> 7) * 32;
    const float* src = &x[(size_t)(qb * 128 + q) * LDX + k0];
#pragma unroll
    for (int c = 0; c < 8; ++c) {
      float4 v = *(const float4*)&src[c * 4];
      Qs[(k0 + c * 4 + 0) * 128 + q] = v.x;
      Qs[(k0 + c * 4 + 1) * 128 + q] = v.y;
      Qs[(k0 + c * 4 + 2) * 128 + q] = v.z;
      Qs[(k0 + c * 4 + 3) * 128 + q] = v.w;
    }
  }

  const int selq = t & 127, part = t >> 7;
  float dreg[KNN]; int ireg[KNN];
#pragma unroll
  for (int r = 0; r < KNN; ++r) { dreg[r] = INFINITY; ireg[r] = 0x7fffffff; }

  for (int tile = 0; tile < 8; ++tile) {
    const int cb = ch * 1024 + tile * 128;
    float acc[8][8] = {};
    for (int kh = 0; kh < 2; ++kh) {
      __syncthreads();  // prev S-reads / prev compute done -> CsS reusable
      {
        const int n = t & 127;
        const int k0 = (t >> 7) * 16;
        const float* src = &x[(size_t)(cb + n) * LDX + kh * 32 + k0];
#pragma unroll
        for (int c = 0; c < 4; ++c) {
          float4 v = *(const float4*)&src[c * 4];
          Cs[(k0 + c * 4 + 0) * 128 + n] = v.x;
          Cs[(k0 + c * 4 + 1) * 128 + n] = v.y;
          Cs[(k0 + c * 4 + 2) * 128 + n] = v.z;
          Cs[(k0 + c * 4 + 3) * 128 + n] = v.w;
        }
      }
      __syncthreads();
#pragma unroll 4
      for (int k2 = 0; k2 < 32; ++k2) {
        const int k = kh * 32 + k2;
        float4 A0 = *(const float4*)&Qs[k * 128 + 4 * am];
        float4 A1 = *(const float4*)&Qs[k * 128 + 4 * am + 64];
        float4 B0 = *(const float4*)&Cs[k2 * 128 + 4 * bg];
        float4 B1 = *(const float4*)&Cs[k2 * 128 + 4 * bg + 64];
        float a[8] = {A0.x, A0.y, A0.z, A0.w, A1.x, A1.y, A1.z, A1.w};
        float b[8] = {B0.x, B0.y, B0.z, B0.w, B1.x, B1.y, B1.z, B1.w};
#pragma unroll
        for (int u = 0; u < 8; ++u)
#pragma unroll
          for (int v = 0; v < 8; ++v) acc[u][v] = fmaf(a[u], b[v], acc[u][v]);
      }
    }
    // sq for my 8 candidates
    float4 s0 = *(const float4*)&sq[cb + 4 * bg];
    float4 s1 = *(const float4*)&sq[cb + 4 * bg + 64];
    float sc[8] = {s0.x, s0.y, s0.z, s0.w, s1.x, s1.y, s1.z, s1.w};

    for (int qr = 0; qr < 4; ++qr) {
      __syncthreads();  // S free (prev phase read / compute done)
      int grp = (qr == (bg >> 3)) ? 0 : (qr == 2 + (bg >> 3)) ? 1 : -1;
      if (grp >= 0) {
        const int cc = (4 * bg) & 31;
#pragma unroll
        for (int u = 0; u < 8; ++u) {
          const int row = 4 * am + (u & 3) + 64 * (u >> 2);
          const int gq = qb * 128 + row;
          const int sw = ((row & 7) ^ ((row >> 2) & 7)) << 2;
          float w[4];
#pragma unroll
          for (int e = 0; e < 4; ++e) {
            const int v = grp * 4 + e;
            const int j = cb + qr * 32 + cc + e;
            float val = fmaf(-2.f, acc[u][v], sc[v]);
            w[e] = (j == gq) ? INFINITY : val;
          }
          *(float4*)&S[row * 32 + (cc ^ sw)] =
              make_float4(w[0], w[1], w[2], w[3]);
        }
      }
      __syncthreads();
      const int swr = ((selq & 7) ^ ((selq >> 2) & 7)) << 2;
      const int jb = cb + qr * 32;
#pragma unroll
      for (int g_ = 0; g_ < 4; ++g_) {
        const int cc = part * 16 + g_ * 4;
        float4 sv = *(const float4*)&S[selq * 32 + (cc ^ swr)];
        float vv[4] = {sv.x, sv.y, sv.z, sv.w};
#pragma unroll
        for (int e = 0; e < 4; ++e) {
          if (vv[e] < dreg[KNN - 1]) insert20(dreg, ireg, vv[e], jb + cc + e);
        }
      }
    }
  }
  // write partial list (16 lists: ch*2 + part)
  const int l = ch * 2 + part;
  float* pdq = pd + ((size_t)l * NPTS + (qb * 128 + selq)) * KNN;
  int* pjq = pj + ((size_t)l * NPTS + (qb * 128 + selq)) * KNN;
#pragma unroll
  for (int r = 0; r < KNN; ++r) { pdq[r] = dreg[r]; pjq[r] = ireg[r]; }
}

// ---------------------------------------------------------------------------
// 3-D kNN pass: thread-per-query streaming over LDS candidate tiles.
// Grid: (32 query-blocks, 8 chunks), 256 threads. 8 partial lists.
// ---------------------------------------------------------------------------
__global__ __launch_bounds__(256) void knn_d3_kernel(
    const float* __restrict__ x, const float* __restrict__ sq,
    float* __restrict__ pd, int* __restrict__ pj) {
  __shared__ float4 Ct[256];  // {x, y, z, sq}
  const int t = threadIdx.x;
  const int q = blockIdx.x * 256 + t;
  const int ch = blockIdx.y;
  const float xi0 = x[q * 3], xi1 = x[q * 3 + 1], xi2 = x[q * 3 + 2];
  float dreg[KNN]; int ireg[KNN];
#pragma unroll
  for (int r = 0; r < KNN; ++r) { dreg[r] = INFINITY; ireg[r] = 0x7fffffff; }

  for (int tile = 0; tile < 4; ++tile) {
    const int cb = ch * 1024 + tile * 256;
    __syncthreads();
    Ct[t] = make_float4(x[(cb + t) * 3], x[(cb + t) * 3 + 1],
                        x[(cb + t) * 3 + 2], sq[cb + t]);
    __syncthreads();
#pragma unroll 1
    for (int c = 0; c < 256; ++c) {
      float4 cv = Ct[c];
      int j = cb + c;
      float val = fmaf(-2.f, xi0 * cv.x + xi1 * cv.y + xi2 * cv.z, cv.w);
      if (j != q && val < dreg[KNN - 1]) insert20(dreg, ireg, val, j);
    }
  }
  float* pdq = pd + ((size_t)ch * NPTS + q) * KNN;
  int* pjq = pj + ((size_t)ch * NPTS + q) * KNN;
#pragma unroll
  for (int r = 0; r < KNN; ++r) { pdq[r] = dreg[r]; pjq[r] = ireg[r]; }
}

// ---------------------------------------------------------------------------
// merge L partial top-20 lists per query -> final 20 indices
// ---------------------------------------------------------------------------
__global__ __launch_bounds__(128) void knn_merge_kernel(
    const float* __restrict__ pd, const int* __restrict__ pj,
    int* __restrict__ idx_out, int L) {
  const int q = blockIdx.x * 128 + threadIdx.x;
  float d[KNN]; int ix[KNN];
#pragma unroll
  for (int r = 0; r < KNN; ++r) { d[r] = INFINITY; ix[r] = 0x7fffffff; }
#pragma unroll 1
  for (int l = 0; l < L; ++l) {
    const float* pdq = pd + ((size_t)l * NPTS + q) * KNN;
    const int* pjq = pj + ((size_t)l * NPTS + q) * KNN;
#pragma unroll 1
    for (int r = 0; r < KNN; ++r) {
      float val = pdq[r]; int j = pjq[r];
      bool worse = (val > d[KNN - 1]) ||
                   (val == d[KNN - 1] && j > ix[KNN - 1]);
      if (!worse) insert20t(d, ix, val, j);
    }
  }
#pragma unroll
  for (int r = 0; r < KNN; ++r) idx_out[(size_t)q * KNN + r] = ix[r];
}

// ---------------------------------------------------------------------------
// edge conv: out[i][c] = max_k relu(b + [x_i, x_j-x_i] . W1[:,c])
// ---------------------------------------------------------------------------
__global__ __launch_bounds__(64) void edgeconv_kernel(
    const float* __restrict__ x, const int* __restrict__ idx,
    const float* __restrict__ W1, const float* __restrict__ b1,
    float* __restrict__ out) {
  const int i = blockIdx.x;
  const int c = threadIdx.x;
  float w0 = W1[c], w1 = W1[64 + c], w2 = W1[128 + c];
  float w3 = W1[192 + c], w4 = W1[256 + c], w5 = W1[320 + c];
  float xi0 = x[3 * i], xi1 = x[3 * i + 1], xi2 = x[3 * i + 2];
  float base = b1[c] + xi0 * w0 + xi1 * w1 + xi2 * w2;
  float m = -INFINITY;
#pragma unroll
  for (int k = 0; k < KNN; ++k) {
    int j = idx[i * KNN + k];
    float d0 = x[3 * j] - xi0, d1 = x[3 * j + 1] - xi1, d2 = x[3 * j + 2] - xi2;
    float h = base + d0 * w3 + d1 * w4 + d2 * w5;
    m = fmaxf(m, fmaxf(h, 0.f));
  }
  out[(size_t)i * 64 + c] = m;
}

// ---------------------------------------------------------------------------
// dilate: dil[c] = max_k xin[idx[k]][c]; out = relu(dil.W + b) - xin
// ---------------------------------------------------------------------------
__global__ __launch_bounds__(64) void dilate_kernel(
    const float* __restrict__ xin, int ldin, const int* __restrict__ idx,
    const float* __restrict__ W, const float* __restrict__ bias,
    float* __restrict__ out, int ldout) {
  const int i = blockIdx.x;
  const int c = threadIdx.x;
  __shared__ float dil[64];
  float m = -INFINITY;
#pragma unroll
  for (int k = 0; k < KNN; ++k) {
    int j = idx[i * KNN + k];
    m = fmaxf(m, xin[(size_t)j * ldin + c]);
  }
  dil[c] = m;
  __syncthreads();
  float acc = bias[c];
#pragma unroll
  for (int d = 0; d < 64; ++d) acc = fmaf(dil[d], W[d * 64 + c], acc);
  out[(size_t)i * ldout + c] = fmaxf(acc, 0.f) - xin[(size_t)i * ldin + c];
}

// ---------------------------------------------------------------------------
// 128x128-tile fp32 GEMM, 256 threads, 8x8/thread, relu epilogue.
// Same conflict-free fragment map as knn_gemm. Requires M%128==N%128==0,
// K%16==0. LDS 16 KB -> high occupancy.
// ---------------------------------------------------------------------------
__global__ __launch_bounds__(256) void gemm128_kernel(
    const float* __restrict__ A, int K, int ldA, const float* __restrict__ W,
    int N, const float* __restrict__ bias, float* __restrict__ C, int ldC,
    int relu) {
  __shared__ float As[16 * 128];  // [k][m]
  __shared__ float Bs[16 * 128];  // [k][n]
  const int t = threadIdx.x;
  const int bn = blockIdx.x * 128;
  const int bm = blockIdx.y * 128;
  const int am = t & 15;
  const int bg = (t >> 4) & 15;
  float acc[8][8] = {};

  for (int k0 = 0; k0 < K; k0 += 16) {
    __syncthreads();
    {  // A: thread loads 8 k-floats of row m = t&127
      const int m = t & 127;
      const int ka = (t >> 7) * 8;
      const float* src = &A[(size_t)(bm + m) * ldA + k0 + ka];
      float4 v0 = *(const float4*)&src[0];
      float4 v1 = *(const float4*)&src[4];
      As[(ka + 0) * 128 + m] = v0.x;
      As[(ka + 1) * 128 + m] = v0.y;
      As[(ka + 2) * 128 + m] = v0.z;
      As[(ka + 3) * 128 + m] = v0.w;
      As[(ka + 4) * 128 + m] = v1.x;
      As[(ka + 5) * 128 + m] = v1.y;
      As[(ka + 6) * 128 + m] = v1.z;
      As[(ka + 7) * 128 + m] = v1.w;
    }
    {  // B: thread loads 8 n-floats of k-row kb = t>>4 (coalesced)
      const int kb = t >> 4;
      const int n8 = (t & 15) * 8;
      const float* src = &W[(size_t)(k0 + kb) * N + bn + n8];
      float4 v0 = *(const float4*)&src[0];
      float4 v1 = *(const float4*)&src[4];
      *(float4*)&Bs[kb * 128 + n8] = v0;
      *(float4*)&Bs[kb * 128 + n8 + 4] = v1;
    }
    __syncthreads();
#pragma unroll
    for (int k = 0; k < 16; ++k) {
      float4 A0 = *(const float4*)&As[k * 128 + 4 * am];
      float4 A1 = *(const float4*)&As[k * 128 + 4 * am + 64];
      float4 B0 = *(const float4*)&Bs[k * 128 + 4 * bg];
      float4 B1 = *(const float4*)&Bs[k * 128 + 4 * bg + 64];
      float a[8] = {A0.x, A0.y, A0.z, A0.w, A1.x, A1.y, A1.z, A1.w};
      float b[8] = {B0.x, B0.y, B0.z, B0.w, B1.x, B1.y, B1.z, B1.w};
#pragma unroll
      for (int u = 0; u < 8; ++u)
#pragma unroll
        for (int v = 0; v < 8; ++v) acc[u][v] = fmaf(a[u], b[v], acc[u][v]);
    }
  }
#pragma unroll
  for (int u = 0; u < 8; ++u) {
    const int m = bm + 4 * am + (u & 3) + 64 * (u >> 2);
#pragma unroll
    for (int vq = 0; vq < 2; ++vq) {
      const int n = bn + 4 * bg + 64 * vq;
      float4 o;
      float* po = (float*)&o;
#pragma unroll
      for (int e = 0; e < 4; ++e) {
        float val = acc[u][vq * 4 + e] + bias[n + e];
        po[e] = relu ? fmaxf(val, 0.f) : val;
      }
      *(float4*)&C[(size_t)m * ldC + n] = o;
    }
  }
}

// ---------------------------------------------------------------------------
// C[M x N] = (relu?) (A[M x K] @ W[K x N] + bias). BM=BN=64, BK=16, 256 thr.
// ---------------------------------------------------------------------------
__global__ __launch_bounds__(256) void gemm_relu_kernel(
    const float* __restrict__ A, int K, int ldA, const float* __restrict__ W,
    int N, const float* __restrict__ bias, float* __restrict__ C, int ldC,
    int relu) {
  __shared__ float As[16][68];
  __shared__ float Bs[16][64];
  const int bn = blockIdx.x * 64;
  const int bm = blockIdx.y * 64;
  const int tid = threadIdx.x;
  const int tx = tid & 15, ty = tid >> 4;
  float acc[4][4] = {};
  for (int k0 = 0; k0 < K; k0 += 16) {
#pragma unroll
    for (int l = tid; l < 1024; l += 256) {
      int m = l >> 4, k = l & 15;
      As[k][m] = A[(size_t)(bm + m) * ldA + k0 + k];
    }
#pragma unroll
    for (int l = tid; l < 1024; l += 256) {
      int n = l & 63, k = l >> 6;
      Bs[k][n] = W[(size_t)(k0 + k) * N + bn + n];
    }
    __syncthreads();
#pragma unroll
    for (int k = 0; k < 16; ++k) {
      float4 av = *(const float4*)&As[k][ty * 4];
      float4 bv = *(const float4*)&Bs[k][tx * 4];
      float a[4] = {av.x, av.y, av.z, av.w};
      float b[4] = {bv.x, bv.y, bv.z, bv.w};
#pragma unroll
      for (int u = 0; u < 4; ++u)
#pragma unroll
        for (int v = 0; v < 4; ++v) acc[u][v] = fmaf(a[u], b[v], acc[u][v]);
    }
    __syncthreads();
  }
#pragma unroll
  for (int u = 0; u < 4; ++u) {
    int m = bm + ty * 4 + u;
#pragma unroll
    for (int v = 0; v < 4; ++v) {
      int n = bn + tx * 4 + v;
      float val = acc[u][v] + bias[n];
      if (relu) val = fmaxf(val, 0.f);
      C[(size_t)m * ldC + n] = val;
    }
  }
}

// ---------------------------------------------------------------------------
// logits = h3 @ Wm3 + bm3 ; out = log_softmax(logits)
// ---------------------------------------------------------------------------
__global__ __launch_bounds__(256) void final_kernel(
    const float* __restrict__ h3, const float* __restrict__ Wm3,
    const float* __restrict__ bm3, float* __restrict__ out) {
  __shared__ float hs[16][132];
  const int tid = threadIdx.x;
  const int r = tid >> 4, c = tid & 15;
  const int row0 = blockIdx.x * 16;
#pragma unroll
  for (int l = tid; l < 2048; l += 256)
    hs[l >> 7][l & 127] = h3[(size_t)row0 * 128 + l];
  __syncthreads();
  float acc = bm3[c];
#pragma unroll
  for (int d = 0; d < 128; ++d) acc = fmaf(hs[r][d], Wm3[d * 16 + c], acc);
  float mx = acc;
#pragma unroll
  for (int o = 8; o >= 1; o >>= 1) mx = fmaxf(mx, __shfl_xor(mx, o, 16));
  float e = expf(acc - mx);
  float s = e;
#pragma unroll
  for (int o = 8; o >= 1; o >>= 1) s += __shfl_xor(s, o, 16);
  out[(size_t)(row0 + r) * 16 + c] = (acc - mx) - logf(s);
}

// ---------------------------------------------------------------------------
extern "C" void kernel_launch(void* const* d_in, const int* in_sizes, int n_in,
                              void* d_out, int out_size, void* d_ws,
                              size_t ws_size, hipStream_t stream) {
  const float* x = (const float*)d_in[0];
  const float* W1 = (const float*)d_in[1];
  const float* b1 = (const float*)d_in[2];
  const float* Wd1 = (const float*)d_in[3];
  const float* bd1 = (const float*)d_in[4];
  const float* Wd2 = (const float*)d_in[5];
  const float* bd2 = (const float*)d_in[6];
  const float* Wd3 = (const float*)d_in[7];
  const float* bd3 = (const float*)d_in[8];
  const float* Wl = (const float*)d_in[9];
  const float* bl = (const float*)d_in[10];
  const float* Wm1 = (const float*)d_in[11];
  const float* bm1 = (const float*)d_in[12];
  const float* Wm2 = (const float*)d_in[13];
  const float* bm2 = (const float*)d_in[14];
  const float* Wm3 = (const float*)d_in[15];
  const float* bm3 = (const float*)d_in[16];
  float* out = (float*)d_out;

  char* ws = (char*)d_ws;
  float* sq = (float*)(ws + 0);              // 32 KB
  int* idxA = (int*)(ws + 32768);            // 640 KB
  float* xfeat = (float*)(ws + 1343488);     // 2 MB   [8192 x 64]
  float* xcat = (float*)(ws + 3440640);      // 6 MB   [8192 x 192]
  float* h1 = (float*)(ws + 9732096);        // 32 MB  [8192 x 1024]
  float* h2 = (float*)(ws + 43286528);       // 8 MB   [8192 x 256]
  float* h3 = (float*)(ws + 51675136);       // 4 MB   [8192 x 128]
  float* x1 = xcat;
  float* x2 = xcat + 64;
  float* x3 = xcat + 128;
  // partial knn lists live in the (not-yet-used) h1 region: 16 lists
  float* pd = h1;                            // 10.5 MB
  int* pj = (int*)(h1 + 16 * NPTS * KNN);    // 10.5 MB

  // stage 1: edge conv on xyz
  sqnorm_kernel<<<32, 256, 0, stream>>>(x, 3, 3, sq);
  knn_d3_kernel<<<dim3(32, 8), 256, 0, stream>>>(x, sq, pd, pj);
  knn_merge_kernel<<<64, 128, 0, stream>>>(pd, pj, idxA, 8);
  edgeconv_kernel<<<NPTS, 64, 0, stream>>>(x, idxA, W1, b1, xfeat);

  // stage 2: three dilate blocks (kNN in 64-D feature space each)
  sqnorm_kernel<<<32, 256, 0, stream>>>(xfeat, 64, 64, sq);
  knn_gemm_kernel<64><<<dim3(64, 8), 256, 0, stream>>>(xfeat, sq, pd, pj);
  knn_merge_kernel<<<64, 128, 0, stream>>>(pd, pj, idxA, 16);
  dilate_kernel<<<NPTS, 64, 0, stream>>>(xfeat, 64, idxA, Wd1, bd1, x1, 192);

  sqnorm_kernel<<<32, 256, 0, stream>>>(x1, 192, 64, sq);
  knn_gemm_kernel<192><<<dim3(64, 8), 256, 0, stream>>>(x1, sq, pd, pj);
  knn_merge_kernel<<<64, 128, 0, stream>>>(pd, pj, idxA, 16);
  dilate_kernel<<<NPTS, 64, 0, stream>>>(x1, 192, idxA, Wd2, bd2, x2, 192);

  sqnorm_kernel<<<32, 256, 0, stream>>>(x2, 192, 64, sq);
  knn_gemm_kernel<192><<<dim3(64, 8), 256, 0, stream>>>(x2, sq, pd, pj);
  knn_merge_kernel<<<64, 128, 0, stream>>>(pd, pj, idxA, 16);
  dilate_kernel<<<NPTS, 64, 0, stream>>>(x2, 192, idxA, Wd3, bd3, x3, 192);

  // stage 3: MLP head
  gemm128_kernel<<<dim3(1024 / 128, NPTS / 128), 256, 0, stream>>>(
      xcat, 192, 192, Wl, 1024, bl, h1, 1024, 1);
  gemm128_kernel<<<dim3(256 / 128, NPTS / 128), 256, 0, stream>>>(
      h1, 1024, 1024, Wm1, 256, bm1, h2, 256, 1);
  gemm_relu_kernel<<<dim3(128 / 64, NPTS / 64), 256, 0, stream>>>(
      h2, 256, 256, Wm2, 128, bm2, h3, 128, 1);
  final_kernel<<<NPTS / 16, 256, 0, stream>>>(h3, Wm3, bm3, out);
}

// Round 5
// 2860.572 us; speedup vs baseline: 11.2958x; 1.0587x over previous
//
#include <hip/hip_runtime.h>
#include <math.h>

#define NPTS 8192
#define KNN 20

// ---------------------------------------------------------------------------
// sq[i] = sum_d x[i][d]^2
// ---------------------------------------------------------------------------
__global__ void sqnorm_kernel(const float* __restrict__ x, int ldx, int D,
                              float* __restrict__ sq) {
  int i = blockIdx.x * blockDim.x + threadIdx.x;
  if (i >= NPTS) return;
  const float* xr = x + (size_t)i * ldx;
  float s = 0.f;
  for (int d = 0; d < D; ++d) { float v = xr[d]; s += v * v; }
  sq[i] = s;
}

// ---------------------------------------------------------------------------
// Branchless sorted-insert (ascending). Caller guards with val < d[19].
// Strict < keeps earlier-scanned (smaller j) entries ahead on ties.
// All indices compile-time (full unroll) -> stays in VGPRs (rule #20).
// ---------------------------------------------------------------------------
__device__ __forceinline__ void insert20(float (&d)[KNN], int (&ix)[KNN],
                                         float val, int j) {
  float cv = val; int ci = j;
#pragma unroll
  for (int r = 0; r < KNN; ++r) {
    bool sw = cv < d[r];
    float od = d[r]; int oi = ix[r];
    d[r] = sw ? cv : od; ix[r] = sw ? ci : oi;
    cv = sw ? od : cv;  ci = sw ? oi : ci;
  }
}

// tie-aware version for the merge (dist, then index)
__device__ __forceinline__ void insert20t(float (&d)[KNN], int (&ix)[KNN],
                                          float val, int j) {
  float cv = val; int ci = j;
#pragma unroll
  for (int r = 0; r < KNN; ++r) {
    bool sw = (cv < d[r]) || (cv == d[r] && ci < ix[r]);
    float od = d[r]; int oi = ix[r];
    d[r] = sw ? cv : od; ix[r] = sw ? ci : oi;
    cv = sw ? od : cv;  ci = sw ? oi : ci;
  }
}

// ---------------------------------------------------------------------------
// 64-D kNN pass: fused fp32 GEMM + top-20 selection.
// Grid: (64 query-blocks, 8 candidate-chunks), 256 threads, 48 KB LDS.
// ROUND-5 FIX: the S-write phase previously indexed acc[u][grp*4+e] with a
// RUNTIME grp -> the compiler allocated acc[8][8] (and sc[8]) in scratch
// (rocprof: 630 MB WRITE_SIZE/dispatch vs 21 MB of real output). Split into
// two statically-indexed branches (BASE = 0 literal / 4 literal) so every
// private-array access is compile-time and lives in VGPRs.
// Fragment map: thread (am = t&15, bg = (t>>4)&15) owns queries
// {4am..4am+3, 64+4am..+3} x cands {4bg..4bg+3, 64+4bg..+3}.
// Score swizzle g(row)=((row&7)^((row>>2)&7))<<2: conflict-free write+read.
// ---------------------------------------------------------------------------
#define WRITE_S(QR, BASE)                                                   \
  {                                                                         \
    const int cc = (4 * bg) & 31;                                           \
    const int jbase = cb + (QR)*32 + cc;                                    \
    _Pragma("unroll") for (int u = 0; u < 8; ++u) {                         \
      const int row = 4 * am + (u & 3) + 64 * (u >> 2);                     \
      const int gq = qb * 128 + row;                                        \
      const int sw = ((row & 7) ^ ((row >> 2) & 7)) << 2;                   \
      float w0 = fmaf(-2.f, acc[u][(BASE) + 0], sc[(BASE) + 0]);            \
      float w1 = fmaf(-2.f, acc[u][(BASE) + 1], sc[(BASE) + 1]);            \
      float w2 = fmaf(-2.f, acc[u][(BASE) + 2], sc[(BASE) + 2]);            \
      float w3 = fmaf(-2.f, acc[u][(BASE) + 3], sc[(BASE) + 3]);            \
      if (jbase + 0 == gq) w0 = INFINITY;                                   \
      if (jbase + 1 == gq) w1 = INFINITY;                                   \
      if (jbase + 2 == gq) w2 = INFINITY;                                   \
      if (jbase + 3 == gq) w3 = INFINITY;                                   \
      *(float4*)&S[row * 32 + (cc ^ sw)] = make_float4(w0, w1, w2, w3);     \
    }                                                                       \
  }

template <int LDX>
__global__ __launch_bounds__(256, 2) void knn_gemm_kernel(
    const float* __restrict__ x, const float* __restrict__ sq,
    float* __restrict__ pd, int* __restrict__ pj) {
  __shared__ float Qs[64 * 128];   // [k][q]
  __shared__ float CsS[32 * 128];  // Cs: [k2][n] during compute; S: [q][cc]
  float* const Cs = CsS;
  float* const S = CsS;
  const int t = threadIdx.x;
  const int qb = blockIdx.x;  // 0..63
  const int ch = blockIdx.y;  // 0..7
  const int am = t & 15;
  const int bg = (t >> 4) & 15;

  // stage Q tile once: thread handles q = t&127, k-half (t>>7)*32
  {
    const int q = t & 127;
    const int k0 = (t >> 7) * 32;
    const float* src = &x[(size_t)(qb * 128 + q) * LDX + k0];
#pragma unroll
    for (int c = 0; c < 8; ++c) {
      float4 v = *(const float4*)&src[c * 4];
      Qs[(k0 + c * 4 + 0) * 128 + q] = v.x;
      Qs[(k0 + c * 4 + 1) * 128 + q] = v.y;
      Qs[(k0 + c * 4 + 2) * 128 + q] = v.z;
      Qs[(k0 + c * 4 + 3) * 128 + q] = v.w;
    }
  }

  const int selq = t & 127, part = t >> 7;
  float dreg[KNN]; int ireg[KNN];
#pragma unroll
  for (int r = 0; r < KNN; ++r) { dreg[r] = INFINITY; ireg[r] = 0x7fffffff; }

  for (int tile = 0; tile < 8; ++tile) {
    const int cb = ch * 1024 + tile * 128;
    float acc[8][8] = {};
    for (int kh = 0; kh < 2; ++kh) {
      __syncthreads();  // prev S-reads / prev compute done -> CsS reusable
      {
        const int n = t & 127;
        const int k0 = (t >> 7) * 16;
        const float* src = &x[(size_t)(cb + n) * LDX + kh * 32 + k0];
#pragma unroll
        for (int c = 0; c < 4; ++c) {
          float4 v = *(const float4*)&src[c * 4];
          Cs[(k0 + c * 4 + 0) * 128 + n] = v.x;
          Cs[(k0 + c * 4 + 1) * 128 + n] = v.y;
          Cs[(k0 + c * 4 + 2) * 128 + n] = v.z;
          Cs[(k0 + c * 4 + 3) * 128 + n] = v.w;
        }
      }
      __syncthreads();
#pragma unroll 4
      for (int k2 = 0; k2 < 32; ++k2) {
        const int k = kh * 32 + k2;
        float4 A0 = *(const float4*)&Qs[k * 128 + 4 * am];
        float4 A1 = *(const float4*)&Qs[k * 128 + 4 * am + 64];
        float4 B0 = *(const float4*)&Cs[k2 * 128 + 4 * bg];
        float4 B1 = *(const float4*)&Cs[k2 * 128 + 4 * bg + 64];
        float a[8] = {A0.x, A0.y, A0.z, A0.w, A1.x, A1.y, A1.z, A1.w};
        float b[8] = {B0.x, B0.y, B0.z, B0.w, B1.x, B1.y, B1.z, B1.w};
#pragma unroll
        for (int u = 0; u < 8; ++u)
#pragma unroll
          for (int v = 0; v < 8; ++v) acc[u][v] = fmaf(a[u], b[v], acc[u][v]);
      }
    }
    // sq for my 8 candidates (compile-time indexed everywhere below)
    float4 s0 = *(const float4*)&sq[cb + 4 * bg];
    float4 s1 = *(const float4*)&sq[cb + 4 * bg + 64];
    float sc[8] = {s0.x, s0.y, s0.z, s0.w, s1.x, s1.y, s1.z, s1.w};

    const int qlow = bg >> 3;  // quarter holding my low 4 candidates
    for (int qr = 0; qr < 4; ++qr) {
      __syncthreads();  // S free (prev phase read / compute done)
      if (qr == qlow) WRITE_S(qr, 0);          // acc[u][0..3], literal base
      if (qr == 2 + qlow) WRITE_S(qr, 4);      // acc[u][4..7], literal base
      __syncthreads();
      const int swr = ((selq & 7) ^ ((selq >> 2) & 7)) << 2;
      const int jb = cb + qr * 32;
#pragma unroll
      for (int g_ = 0; g_ < 4; ++g_) {
        const int cc = part * 16 + g_ * 4;
        float4 sv = *(const float4*)&S[selq * 32 + (cc ^ swr)];
        float vv[4] = {sv.x, sv.y, sv.z, sv.w};
#pragma unroll
        for (int e = 0; e < 4; ++e) {
          if (vv[e] < dreg[KNN - 1]) insert20(dreg, ireg, vv[e], jb + cc + e);
        }
      }
    }
  }
  // write partial list (16 lists: ch*2 + part)
  const int l = ch * 2 + part;
  float* pdq = pd + ((size_t)l * NPTS + (qb * 128 + selq)) * KNN;
  int* pjq = pj + ((size_t)l * NPTS + (qb * 128 + selq)) * KNN;
#pragma unroll
  for (int r = 0; r < KNN; ++r) { pdq[r] = dreg[r]; pjq[r] = ireg[r]; }
}

// ---------------------------------------------------------------------------
// 3-D kNN pass: thread-per-query streaming over LDS candidate tiles.
// Grid: (32 query-blocks, 8 chunks), 256 threads. 8 partial lists.
// ---------------------------------------------------------------------------
__global__ __launch_bounds__(256) void knn_d3_kernel(
    const float* __restrict__ x, const float* __restrict__ sq,
    float* __restrict__ pd, int* __restrict__ pj) {
  __shared__ float4 Ct[256];  // {x, y, z, sq}
  const int t = threadIdx.x;
  const int q = blockIdx.x * 256 + t;
  const int ch = blockIdx.y;
  const float xi0 = x[q * 3], xi1 = x[q * 3 + 1], xi2 = x[q * 3 + 2];
  float dreg[KNN]; int ireg[KNN];
#pragma unroll
  for (int r = 0; r < KNN; ++r) { dreg[r] = INFINITY; ireg[r] = 0x7fffffff; }

  for (int tile = 0; tile < 4; ++tile) {
    const int cb = ch * 1024 + tile * 256;
    __syncthreads();
    Ct[t] = make_float4(x[(cb + t) * 3], x[(cb + t) * 3 + 1],
                        x[(cb + t) * 3 + 2], sq[cb + t]);
    __syncthreads();
#pragma unroll 1
    for (int c = 0; c < 256; ++c) {
      float4 cv = Ct[c];
      int j = cb + c;
      float val = fmaf(-2.f, xi0 * cv.x + xi1 * cv.y + xi2 * cv.z, cv.w);
      if (j != q && val < dreg[KNN - 1]) insert20(dreg, ireg, val, j);
    }
  }
  float* pdq = pd + ((size_t)ch * NPTS + q) * KNN;
  int* pjq = pj + ((size_t)ch * NPTS + q) * KNN;
#pragma unroll
  for (int r = 0; r < KNN; ++r) { pdq[r] = dreg[r]; pjq[r] = ireg[r]; }
}

// ---------------------------------------------------------------------------
// merge L partial top-20 lists per query -> final 20 indices
// ---------------------------------------------------------------------------
__global__ __launch_bounds__(128) void knn_merge_kernel(
    const float* __restrict__ pd, const int* __restrict__ pj,
    int* __restrict__ idx_out, int L) {
  const int q = blockIdx.x * 128 + threadIdx.x;
  float d[KNN]; int ix[KNN];
#pragma unroll
  for (int r = 0; r < KNN; ++r) { d[r] = INFINITY; ix[r] = 0x7fffffff; }
#pragma unroll 1
  for (int l = 0; l < L; ++l) {
    const float* pdq = pd + ((size_t)l * NPTS + q) * KNN;
    const int* pjq = pj + ((size_t)l * NPTS + q) * KNN;
#pragma unroll 1
    for (int r = 0; r < KNN; ++r) {
      float val = pdq[r]; int j = pjq[r];
      bool worse = (val > d[KNN - 1]) ||
                   (val == d[KNN - 1] && j > ix[KNN - 1]);
      if (!worse) insert20t(d, ix, val, j);
    }
  }
#pragma unroll
  for (int r = 0; r < KNN; ++r) idx_out[(size_t)q * KNN + r] = ix[r];
}

// ---------------------------------------------------------------------------
// edge conv: out[i][c] = max_k relu(b + [x_i, x_j-x_i] . W1[:,c])
// ---------------------------------------------------------------------------
__global__ __launch_bounds__(64) void edgeconv_kernel(
    const float* __restrict__ x, const int* __restrict__ idx,
    const float* __restrict__ W1, const float* __restrict__ b1,
    float* __restrict__ out) {
  const int i = blockIdx.x;
  const int c = threadIdx.x;
  float w0 = W1[c], w1 = W1[64 + c], w2 = W1[128 + c];
  float w3 = W1[192 + c], w4 = W1[256 + c], w5 = W1[320 + c];
  float xi0 = x[3 * i], xi1 = x[3 * i + 1], xi2 = x[3 * i + 2];
  float base = b1[c] + xi0 * w0 + xi1 * w1 + xi2 * w2;
  float m = -INFINITY;
#pragma unroll
  for (int k = 0; k < KNN; ++k) {
    int j = idx[i * KNN + k];
    float d0 = x[3 * j] - xi0, d1 = x[3 * j + 1] - xi1, d2 = x[3 * j + 2] - xi2;
    float h = base + d0 * w3 + d1 * w4 + d2 * w5;
    m = fmaxf(m, fmaxf(h, 0.f));
  }
  out[(size_t)i * 64 + c] = m;
}

// ---------------------------------------------------------------------------
// dilate: dil[c] = max_k xin[idx[k]][c]; out = relu(dil.W + b) - xin
// ---------------------------------------------------------------------------
__global__ __launch_bounds__(64) void dilate_kernel(
    const float* __restrict__ xin, int ldin, const int* __restrict__ idx,
    const float* __restrict__ W, const float* __restrict__ bias,
    float* __restrict__ out, int ldout) {
  const int i = blockIdx.x;
  const int c = threadIdx.x;
  __shared__ float dil[64];
  float m = -INFINITY;
#pragma unroll
  for (int k = 0; k < KNN; ++k) {
    int j = idx[i * KNN + k];
    m = fmaxf(m, xin[(size_t)j * ldin + c]);
  }
  dil[c] = m;
  __syncthreads();
  float acc = bias[c];
#pragma unroll
  for (int d = 0; d < 64; ++d) acc = fmaf(dil[d], W[d * 64 + c], acc);
  out[(size_t)i * ldout + c] = fmaxf(acc, 0.f) - xin[(size_t)i * ldin + c];
}

// ---------------------------------------------------------------------------
// 128x128-tile fp32 GEMM, 256 threads, 8x8/thread, relu epilogue.
// Requires M%128==N%128==0, K%16==0. LDS 16 KB -> high occupancy.
// ---------------------------------------------------------------------------
__global__ __launch_bounds__(256) void gemm128_kernel(
    const float* __restrict__ A, int K, int ldA, const float* __restrict__ W,
    int N, const float* __restrict__ bias, float* __restrict__ C, int ldC,
    int relu) {
  __shared__ float As[16 * 128];  // [k][m]
  __shared__ float Bs[16 * 128];  // [k][n]
  const int t = threadIdx.x;
  const int bn = blockIdx.x * 128;
  const int bm = blockIdx.y * 128;
  const int am = t & 15;
  const int bg = (t >> 4) & 15;
  float acc[8][8] = {};

  for (int k0 = 0; k0 < K; k0 += 16) {
    __syncthreads();
    {  // A: thread loads 8 k-floats of row m = t&127
      const int m = t & 127;
      const int ka = (t >> 7) * 8;
      const float* src = &A[(size_t)(bm + m) * ldA + k0 + ka];
      float4 v0 = *(const float4*)&src[0];
      float4 v1 = *(const float4*)&src[4];
      As[(ka + 0) * 128 + m] = v0.x;
      As[(ka + 1) * 128 + m] = v0.y;
      As[(ka + 2) * 128 + m] = v0.z;
      As[(ka + 3) * 128 + m] = v0.w;
      As[(ka + 4) * 128 + m] = v1.x;
      As[(ka + 5) * 128 + m] = v1.y;
      As[(ka + 6) * 128 + m] = v1.z;
      As[(ka + 7) * 128 + m] = v1.w;
    }
    {  // B: thread loads 8 n-floats of k-row kb = t>>4 (coalesced)
      const int kb = t >> 4;
      const int n8 = (t & 15) * 8;
      const float* src = &W[(size_t)(k0 + kb) * N + bn + n8];
      float4 v0 = *(const float4*)&src[0];
      float4 v1 = *(const float4*)&src[4];
      *(float4*)&Bs[kb * 128 + n8] = v0;
      *(float4*)&Bs[kb * 128 + n8 + 4] = v1;
    }
    __syncthreads();
#pragma unroll
    for (int k = 0; k < 16; ++k) {
      float4 A0 = *(const float4*)&As[k * 128 + 4 * am];
      float4 A1 = *(const float4*)&As[k * 128 + 4 * am + 64];
      float4 B0 = *(const float4*)&Bs[k * 128 + 4 * bg];
      float4 B1 = *(const float4*)&Bs[k * 128 + 4 * bg + 64];
      float a[8] = {A0.x, A0.y, A0.z, A0.w, A1.x, A1.y, A1.z, A1.w};
      float b[8] = {B0.x, B0.y, B0.z, B0.w, B1.x, B1.y, B1.z, B1.w};
#pragma unroll
      for (int u = 0; u < 8; ++u)
#pragma unroll
        for (int v = 0; v < 8; ++v) acc[u][v] = fmaf(a[u], b[v], acc[u][v]);
    }
  }
#pragma unroll
  for (int u = 0; u < 8; ++u) {
    const int m = bm + 4 * am + (u & 3) + 64 * (u >> 2);
#pragma unroll
    for (int vq = 0; vq < 2; ++vq) {
      const int n = bn + 4 * bg + 64 * vq;
      float4 o;
      float* po = (float*)&o;
#pragma unroll
      for (int e = 0; e < 4; ++e) {
        float val = acc[u][vq * 4 + e] + bias[n + e];
        po[e] = relu ? fmaxf(val, 0.f) : val;
      }
      *(float4*)&C[(size_t)m * ldC + n] = o;
    }
  }
}

// ---------------------------------------------------------------------------
// C[M x N] = (relu?) (A[M x K] @ W[K x N] + bias). BM=BN=64, BK=16, 256 thr.
// ---------------------------------------------------------------------------
__global__ __launch_bounds__(256) void gemm_relu_kernel(
    const float* __restrict__ A, int K, int ldA, const float* __restrict__ W,
    int N, const float* __restrict__ bias, float* __restrict__ C, int ldC,
    int relu) {
  __shared__ float As[16][68];
  __shared__ float Bs[16][64];
  const int bn = blockIdx.x * 64;
  const int bm = blockIdx.y * 64;
  const int tid = threadIdx.x;
  const int tx = tid & 15, ty = tid >> 4;
  float acc[4][4] = {};
  for (int k0 = 0; k0 < K; k0 += 16) {
#pragma unroll
    for (int l = tid; l < 1024; l += 256) {
      int m = l >> 4, k = l & 15;
      As[k][m] = A[(size_t)(bm + m) * ldA + k0 + k];
    }
#pragma unroll
    for (int l = tid; l < 1024; l += 256) {
      int n = l & 63, k = l >> 6;
      Bs[k][n] = W[(size_t)(k0 + k) * N + bn + n];
    }
    __syncthreads();
#pragma unroll
    for (int k = 0; k < 16; ++k) {
      float4 av = *(const float4*)&As[k][ty * 4];
      float4 bv = *(const float4*)&Bs[k][tx * 4];
      float a[4] = {av.x, av.y, av.z, av.w};
      float b[4] = {bv.x, bv.y, bv.z, bv.w};
#pragma unroll
      for (int u = 0; u < 4; ++u)
#pragma unroll
        for (int v = 0; v < 4; ++v) acc[u][v] = fmaf(a[u], b[v], acc[u][v]);
    }
    __syncthreads();
  }
#pragma unroll
  for (int u = 0; u < 4; ++u) {
    int m = bm + ty * 4 + u;
#pragma unroll
    for (int v = 0; v < 4; ++v) {
      int n = bn + tx * 4 + v;
      float val = acc[u][v] + bias[n];
      if (relu) val = fmaxf(val, 0.f);
      C[(size_t)m * ldC + n] = val;
    }
  }
}

// ---------------------------------------------------------------------------
// logits = h3 @ Wm3 + bm3 ; out = log_softmax(logits)
// ---------------------------------------------------------------------------
__global__ __launch_bounds__(256) void final_kernel(
    const float* __restrict__ h3, const float* __restrict__ Wm3,
    const float* __restrict__ bm3, float* __restrict__ out) {
  __shared__ float hs[16][132];
  const int tid = threadIdx.x;
  const int r = tid >> 4, c = tid & 15;
  const int row0 = blockIdx.x * 16;
#pragma unroll
  for (int l = tid; l < 2048; l += 256)
    hs[l >> 7][l & 127] = h3[(size_t)row0 * 128 + l];
  __syncthreads();
  float acc = bm3[c];
#pragma unroll
  for (int d = 0; d < 128; ++d) acc = fmaf(hs[r][d], Wm3[d * 16 + c], acc);
  float mx = acc;
#pragma unroll
  for (int o = 8; o >= 1; o >>= 1) mx = fmaxf(mx, __shfl_xor(mx, o, 16));
  float e = expf(acc - mx);
  float s = e;
#pragma unroll
  for (int o = 8; o >= 1; o >>= 1) s += __shfl_xor(s, o, 16);
  out[(size_t)(row0 + r) * 16 + c] = (acc - mx) - logf(s);
}

// ---------------------------------------------------------------------------
extern "C" void kernel_launch(void* const* d_in, const int* in_sizes, int n_in,
                              void* d_out, int out_size, void* d_ws,
                              size_t ws_size, hipStream_t stream) {
  const float* x = (const float*)d_in[0];
  const float* W1 = (const float*)d_in[1];
  const float* b1 = (const float*)d_in[2];
  const float* Wd1 = (const float*)d_in[3];
  const float* bd1 = (const float*)d_in[4];
  const float* Wd2 = (const float*)d_in[5];
  const float* bd2 = (const float*)d_in[6];
  const float* Wd3 = (const float*)d_in[7];
  const float* bd3 = (const float*)d_in[8];
  const float* Wl = (const float*)d_in[9];
  const float* bl = (const float*)d_in[10];
  const float* Wm1 = (const float*)d_in[11];
  const float* bm1 = (const float*)d_in[12];
  const float* Wm2 = (const float*)d_in[13];
  const float* bm2 = (const float*)d_in[14];
  const float* Wm3 = (const float*)d_in[15];
  const float* bm3 = (const float*)d_in[16];
  float* out = (float*)d_out;

  char* ws = (char*)d_ws;
  float* sq = (float*)(ws + 0);              // 32 KB
  int* idxA = (int*)(ws + 32768);            // 640 KB
  float* xfeat = (float*)(ws + 1343488);     // 2 MB   [8192 x 64]
  float* xcat = (float*)(ws + 3440640);      // 6 MB   [8192 x 192]
  float* h1 = (float*)(ws + 9732096);        // 32 MB  [8192 x 1024]
  float* h2 = (float*)(ws + 43286528);       // 8 MB   [8192 x 256]
  float* h3 = (float*)(ws + 51675136);       // 4 MB   [8192 x 128]
  float* x1 = xcat;
  float* x2 = xcat + 64;
  float* x3 = xcat + 128;
  // partial knn lists live in the (not-yet-used) h1 region: 16 lists
  float* pd = h1;                            // 10.5 MB
  int* pj = (int*)(h1 + 16 * NPTS * KNN);    // 10.5 MB

  // stage 1: edge conv on xyz
  sqnorm_kernel<<<32, 256, 0, stream>>>(x, 3, 3, sq);
  knn_d3_kernel<<<dim3(32, 8), 256, 0, stream>>>(x, sq, pd, pj);
  knn_merge_kernel<<<64, 128, 0, stream>>>(pd, pj, idxA, 8);
  edgeconv_kernel<<<NPTS, 64, 0, stream>>>(x, idxA, W1, b1, xfeat);

  // stage 2: three dilate blocks (kNN in 64-D feature space each)
  sqnorm_kernel<<<32, 256, 0, stream>>>(xfeat, 64, 64, sq);
  knn_gemm_kernel<64><<<dim3(64, 8), 256, 0, stream>>>(xfeat, sq, pd, pj);
  knn_merge_kernel<<<64, 128, 0, stream>>>(pd, pj, idxA, 16);
  dilate_kernel<<<NPTS, 64, 0, stream>>>(xfeat, 64, idxA, Wd1, bd1, x1, 192);

  sqnorm_kernel<<<32, 256, 0, stream>>>(x1, 192, 64, sq);
  knn_gemm_kernel<192><<<dim3(64, 8), 256, 0, stream>>>(x1, sq, pd, pj);
  knn_merge_kernel<<<64, 128, 0, stream>>>(pd, pj, idxA, 16);
  dilate_kernel<<<NPTS, 64, 0, stream>>>(x1, 192, idxA, Wd2, bd2, x2, 192);

  sqnorm_kernel<<<32, 256, 0, stream>>>(x2, 192, 64, sq);
  knn_gemm_kernel<192><<<dim3(64, 8), 256, 0, stream>>>(x2, sq, pd, pj);
  knn_merge_kernel<<<64, 128, 0, stream>>>(pd, pj, idxA, 16);
  dilate_kernel<<<NPTS, 64, 0, stream>>>(x2, 192, idxA, Wd3, bd3, x3, 192);

  // stage 3: MLP head
  gemm128_kernel<<<dim3(1024 / 128, NPTS / 128), 256, 0, stream>>>(
      xcat, 192, 192, Wl, 1024, bl, h1, 1024, 1);
  gemm128_kernel<<<dim3(256 / 128, NPTS / 128), 256, 0, stream>>>(
      h1, 1024, 1024, Wm1, 256, bm1, h2, 256, 1);
  gemm_relu_kernel<<<dim3(128 / 64, NPTS / 64), 256, 0, stream>>>(
      h2, 256, 256, Wm2, 128, bm2, h3, 128, 1);
  final_kernel<<<NPTS / 16, 256, 0, stream>>>(h3, Wm3, bm3, out);
}